// Round 3
// baseline (498.729 us; speedup 1.0000x reference)
//
#include <hip/hip_runtime.h>
#include <hip/hip_bf16.h>

#define S_LEN 2048
#define HID   2048
#define NH    32
#define NKV   8
#define HD    64
#define ROT   16
#define QKV_N 3072
#define ROWS  4096   // B*S

typedef __attribute__((ext_vector_type(8))) short short8;
typedef __attribute__((ext_vector_type(8))) unsigned short ushort8;
typedef __attribute__((ext_vector_type(4))) float floatx4;

static __device__ __forceinline__ float bf2f(ushort u) {
  union { unsigned int i; float f; } v; v.i = ((unsigned int)u) << 16; return v.f;
}
static __device__ __forceinline__ ushort f2bf(float f) {
  union { __hip_bfloat16 h; ushort u; } v; v.h = __float2bfloat16(f); return v.u;
}

// ---------------------------------------------------------------------------
// fp32 -> bf16 convert, 8 elems/thread (inputs are fp32)
// ---------------------------------------------------------------------------
__global__ __launch_bounds__(256)
void cvt_f32_bf16(const float* __restrict__ in, ushort* __restrict__ out, int n8) {
  const int i = blockIdx.x * 256 + threadIdx.x;
  if (i >= n8) return;
  const float4 a = ((const float4*)in)[2 * i];
  const float4 b = ((const float4*)in)[2 * i + 1];
  ushort8 o;
  o[0] = f2bf(a.x); o[1] = f2bf(a.y); o[2] = f2bf(a.z); o[3] = f2bf(a.w);
  o[4] = f2bf(b.x); o[5] = f2bf(b.y); o[6] = f2bf(b.z); o[7] = f2bf(b.w);
  ((ushort8*)out)[i] = o;
}

// ---------------------------------------------------------------------------
// NT GEMM (m97 structure): 128x128 tile, BK=32, global_load_lds width-16,
// 4 waves x 4x4 mfma_f32_16x16x32_bf16. OUT_BF16 ? bf16 C : fp32 C.
// ---------------------------------------------------------------------------
template<bool OUT_BF16>
__global__ __launch_bounds__(256, 2)
void gemm_nt(const ushort* __restrict__ A, const ushort* __restrict__ B,
             void* __restrict__ Cout, int M, int N, int K) {
  __shared__ ushort lA[128 * 32];
  __shared__ ushort lB[128 * 32];
  const int tid  = threadIdx.x;
  const int wave = tid >> 6, lane = tid & 63;
  const int wr = (wave >> 1) * 64, wc = (wave & 1) * 64;
  const int frow = lane & 15, quad = lane >> 4;
  const int fk = quad * 8;
  const int srow = lane >> 2, skk = (lane & 3) * 8;
  const size_t bm = (size_t)blockIdx.y * 128;
  const size_t bn = (size_t)blockIdx.x * 128;
  const ushort* Ab = A + bm * K;
  const ushort* Bb = B + bn * K;
  floatx4 acc[4][4] = {};

  for (int k0 = 0; k0 < K; k0 += 32) {
    __syncthreads();
    {
      const int c0 = wave * 2;
      const ushort* ga = Ab + (size_t)(c0 * 16 + srow) * K + (k0 + skk);
      const ushort* gb = Bb + (size_t)(c0 * 16 + srow) * K + (k0 + skk);
      __builtin_amdgcn_global_load_lds((const __attribute__((address_space(1))) void*)ga,
          (__attribute__((address_space(3))) void*)&lA[c0 * 512], 16, 0, 0);
      __builtin_amdgcn_global_load_lds((const __attribute__((address_space(1))) void*)gb,
          (__attribute__((address_space(3))) void*)&lB[c0 * 512], 16, 0, 0);
      __builtin_amdgcn_global_load_lds((const __attribute__((address_space(1))) void*)(ga + (size_t)16 * K),
          (__attribute__((address_space(3))) void*)&lA[(c0 + 1) * 512], 16, 0, 0);
      __builtin_amdgcn_global_load_lds((const __attribute__((address_space(1))) void*)(gb + (size_t)16 * K),
          (__attribute__((address_space(3))) void*)&lB[(c0 + 1) * 512], 16, 0, 0);
    }
    __syncthreads();

    short8 af[4], bfr[4];
#pragma unroll
    for (int i = 0; i < 4; ++i)
      af[i] = *(const short8*)&lA[(wr + i * 16 + frow) * 32 + fk];
#pragma unroll
    for (int i = 0; i < 4; ++i)
      bfr[i] = *(const short8*)&lB[(wc + i * 16 + frow) * 32 + fk];
#pragma unroll
    for (int i = 0; i < 4; ++i)
#pragma unroll
      for (int j = 0; j < 4; ++j)
        acc[i][j] = __builtin_amdgcn_mfma_f32_16x16x32_bf16(af[i], bfr[j], acc[i][j], 0, 0, 0);
  }

  const int r0 = quad * 4;
#pragma unroll
  for (int i = 0; i < 4; ++i) {
#pragma unroll
    for (int r = 0; r < 4; ++r) {
      const size_t row = bm + wr + i * 16 + r0 + r;
#pragma unroll
      for (int j = 0; j < 4; ++j) {
        const size_t col = bn + wc + j * 16 + frow;
        if (OUT_BF16) ((ushort*)Cout)[row * N + col] = f2bf(acc[i][j][r]);
        else          ((float*)Cout)[row * N + col] = acc[i][j][r];
      }
    }
  }
}

// ---------------------------------------------------------------------------
// Per-head LayerNorm + partial NeoX RoPE + split. One wave per (row, slot).
// slot 0..31 = q, 32..39 = k, 40..47 = v. LN weights fp32.
// Q -> (b,h,s,d); K -> (b,kv,s,d); V -> (b,kv,d,s) transposed for flash.
// ---------------------------------------------------------------------------
__global__ __launch_bounds__(256)
void ln_rope_split(const ushort* __restrict__ qkv, const int* __restrict__ pos_ids,
                   const float* __restrict__ qw, const float* __restrict__ kw,
                   ushort* __restrict__ Q, ushort* __restrict__ Kk, ushort* __restrict__ Vt) {
  const int gw   = (blockIdx.x * 256 + threadIdx.x) >> 6;
  const int lane = threadIdx.x & 63;
  const int row  = gw / 48;
  const int slot = gw - row * 48;
  const int b = row >> 11, s = row & 2047;
  const float x = bf2f(qkv[(size_t)row * QKV_N + slot * 64 + lane]);

  if (slot < 40) {
    float s1 = x, s2 = x * x;
#pragma unroll
    for (int d = 1; d < 64; d <<= 1) { s1 += __shfl_xor(s1, d); s2 += __shfl_xor(s2, d); }
    const float mu  = s1 * (1.0f / 64.0f);
    const float var = s2 * (1.0f / 64.0f) - mu * mu;
    const float w = (slot < 32) ? qw[slot * 64 + lane] : kw[(slot - 32) * 64 + lane];
    float y = (x - mu) * rsqrtf(var + 1e-5f) * w;
    if (lane < ROT) {
      const int dd = lane & 7;
      const float invf = powf(10000.0f, -(float)dd * 0.125f);
      const float fr = (float)pos_ids[row] * invf;
      const float c = cosf(fr), sn = sinf(fr);
      const float yp = __shfl_xor(y, 8);
      y = (lane < 8) ? (y * c - yp * sn) : (y * c + yp * sn);
    }
    if (slot < 32)
      Q[(((size_t)b * NH + slot) * S_LEN + s) * HD + lane] = f2bf(y);
    else
      Kk[(((size_t)b * NKV + (slot - 32)) * S_LEN + s) * HD + lane] = f2bf(y);
  } else {
    const int kvh = slot - 40;
    Vt[(((size_t)b * NKV + kvh) * HD + lane) * S_LEN + s] = f2bf(x);
  }
}

// ---------------------------------------------------------------------------
// Causal GQA flash attention, FIXED-CAP softmax (no online rescaling):
// LayerNorm bounds |q|,|k| <= 8 -> s = q.k/8 in [-8.1,8.1]; p = exp(s - 9)
// cannot overflow; softmax shift-invariance makes it exact.
//
// v4 structure (kill the LDS P-bounce — v3's per-body ds_write x16 +
// wave_barrier + lgkmcnt(0) drain + ds_read was the serialization floor):
//  * Swapped QK^T: S^T = mfma(K, Q) puts q on frow, k on (quad,reg).
//    Softmax denom becomes lane-local adds (+ 2 shfl_xor at the end).
//  * In-register P regroup (T12 adapted to 16x16): 4x v_cvt_pk_bf16_f32
//    + 8 ds_bpermute (<=2-way, free) + 4 cndmask build the PV A-fragment
//    (k at quad*8 granularity) from the S^T accumulator (quad*4).
//    PV = mfma(pfrag, v) -> same V loads, same O layout/epilogue as v3.
//    No barriers, no waitcnt drains, no P LDS.
//  * Diagonal-only masking: tiles t <= T-2 are fully causal-valid; only
//    t = T-1 runs the masked body (drops 16 cmp+cndmask elsewhere).
//  * LDS 18.9 -> 10.5 KB; __launch_bounds__(128,4) pins VGPR<=128 ->
//    4 waves/SIMD cap.
//  * Retains v3: split-K 2-wave blocks + additive combine, LPT grid,
//    XCD-locality remap, K reg double-buffer, V issue-early/use-late.
// ---------------------------------------------------------------------------
#define SMAX 9.0f

// Regroup P from S^T-accumulator layout (q=frow, k=quad*4+r; pa=k 0..15,
// pb=k 16..31) into the PV A-operand layout (q=frow, k=quad*8+0..7).
static __device__ __forceinline__ short8 build_pfrag(floatx4 pa, floatx4 pb,
                                                     int frow, int quad) {
  int w0, w1, w2, w3;
  asm("v_cvt_pk_bf16_f32 %0, %1, %2" : "=v"(w0) : "v"(pa[0]), "v"(pa[1]));
  asm("v_cvt_pk_bf16_f32 %0, %1, %2" : "=v"(w1) : "v"(pa[2]), "v"(pa[3]));
  asm("v_cvt_pk_bf16_f32 %0, %1, %2" : "=v"(w2) : "v"(pb[0]), "v"(pb[1]));
  asm("v_cvt_pk_bf16_f32 %0, %1, %2" : "=v"(w3) : "v"(pb[2]), "v"(pb[3]));
  const int sA = frow + ((quad & 1) << 5);   // src quad 0 or 2
  const int sB = sA + 16;                    // src quad 1 or 3
  const int t0 = __shfl(w0, sA), t1 = __shfl(w1, sA);
  const int t2 = __shfl(w0, sB), t3 = __shfl(w1, sB);
  const int u0 = __shfl(w2, sA), u1 = __shfl(w3, sA);
  const int u2 = __shfl(w2, sB), u3 = __shfl(w3, sB);
  const bool lo = quad < 2;                  // k<16 half vs k>=16 half
  union { int i[4]; short8 s; } r;
  r.i[0] = lo ? t0 : u0;
  r.i[1] = lo ? t1 : u1;
  r.i[2] = lo ? t2 : u2;
  r.i[3] = lo ? t3 : u3;
  return r.s;
}

#define FA_BODY(KC0,KC1,KC2,KC3, KN0,KN1,KN2,KN3, TI, MASKED)                  \
  {                                                                            \
    const int jj = (TI) * 32;                                                  \
    const short8 v0 = *(const short8*)&Vb[(size_t)( 0 + frow) * S_LEN + jj + fk]; \
    const short8 v1 = *(const short8*)&Vb[(size_t)(16 + frow) * S_LEN + jj + fk]; \
    const short8 v2 = *(const short8*)&Vb[(size_t)(32 + frow) * S_LEN + jj + fk]; \
    const short8 v3 = *(const short8*)&Vb[(size_t)(48 + frow) * S_LEN + jj + fk]; \
    const floatx4 z = {};                                                      \
    floatx4 st00 = __builtin_amdgcn_mfma_f32_16x16x32_bf16(KC0, q00, z, 0, 0, 0); \
    st00 = __builtin_amdgcn_mfma_f32_16x16x32_bf16(KC1, q01, st00, 0, 0, 0);   \
    floatx4 st01 = __builtin_amdgcn_mfma_f32_16x16x32_bf16(KC2, q00, z, 0, 0, 0); \
    st01 = __builtin_amdgcn_mfma_f32_16x16x32_bf16(KC3, q01, st01, 0, 0, 0);   \
    floatx4 st10 = __builtin_amdgcn_mfma_f32_16x16x32_bf16(KC0, q10, z, 0, 0, 0); \
    st10 = __builtin_amdgcn_mfma_f32_16x16x32_bf16(KC1, q11, st10, 0, 0, 0);   \
    floatx4 st11 = __builtin_amdgcn_mfma_f32_16x16x32_bf16(KC2, q10, z, 0, 0, 0); \
    st11 = __builtin_amdgcn_mfma_f32_16x16x32_bf16(KC3, q11, st11, 0, 0, 0);   \
    if ((TI) + 1 < tb) {                                                       \
      const int jn = ((TI) + 1) * 32;                                          \
      KN0 = *(const short8*)&Kb[(size_t)(jn + frow) * HD + fk];                \
      KN1 = *(const short8*)&Kb[(size_t)(jn + frow) * HD + 32 + fk];           \
      KN2 = *(const short8*)&Kb[(size_t)(jn + 16 + frow) * HD + fk];           \
      KN3 = *(const short8*)&Kb[(size_t)(jn + 16 + frow) * HD + 32 + fk];      \
    }                                                                          \
    floatx4 p00, p01, p10, p11;                                                \
    _Pragma("unroll")                                                          \
    for (int r = 0; r < 4; ++r) {                                              \
      if (MASKED) {                                                            \
        const int kg0 = jj + quad * 4 + r;                                     \
        const int kg1 = kg0 + 16;                                              \
        p00[r] = (kg0 <= qm + frow)      ? __expf(st00[r] * 0.125f - SMAX) : 0.0f; \
        p01[r] = (kg1 <= qm + frow)      ? __expf(st01[r] * 0.125f - SMAX) : 0.0f; \
        p10[r] = (kg0 <= qm + 16 + frow) ? __expf(st10[r] * 0.125f - SMAX) : 0.0f; \
        p11[r] = (kg1 <= qm + 16 + frow) ? __expf(st11[r] * 0.125f - SMAX) : 0.0f; \
      } else {                                                                 \
        p00[r] = __expf(st00[r] * 0.125f - SMAX);                              \
        p01[r] = __expf(st01[r] * 0.125f - SMAX);                              \
        p10[r] = __expf(st10[r] * 0.125f - SMAX);                              \
        p11[r] = __expf(st11[r] * 0.125f - SMAX);                              \
      }                                                                        \
      lp0 += p00[r] + p01[r];                                                  \
      lp1 += p10[r] + p11[r];                                                  \
    }                                                                          \
    const short8 pf0 = build_pfrag(p00, p01, frow, quad);                      \
    const short8 pf1 = build_pfrag(p10, p11, frow, quad);                      \
    o00 = __builtin_amdgcn_mfma_f32_16x16x32_bf16(pf0, v0, o00, 0, 0, 0);      \
    o01 = __builtin_amdgcn_mfma_f32_16x16x32_bf16(pf0, v1, o01, 0, 0, 0);      \
    o02 = __builtin_amdgcn_mfma_f32_16x16x32_bf16(pf0, v2, o02, 0, 0, 0);      \
    o03 = __builtin_amdgcn_mfma_f32_16x16x32_bf16(pf0, v3, o03, 0, 0, 0);      \
    o10 = __builtin_amdgcn_mfma_f32_16x16x32_bf16(pf1, v0, o10, 0, 0, 0);      \
    o11 = __builtin_amdgcn_mfma_f32_16x16x32_bf16(pf1, v1, o11, 0, 0, 0);      \
    o12 = __builtin_amdgcn_mfma_f32_16x16x32_bf16(pf1, v2, o12, 0, 0, 0);      \
    o13 = __builtin_amdgcn_mfma_f32_16x16x32_bf16(pf1, v3, o13, 0, 0, 0);      \
  }

__global__ __launch_bounds__(128, 4)
void flash_attn(const ushort* __restrict__ Q, const ushort* __restrict__ Kk,
                const ushort* __restrict__ Vt, ushort* __restrict__ O) {
  __shared__ float obuf[64 * 33];
  __shared__ float lpbuf[64 * 8];
  const int wave = threadIdx.x >> 6, lane = threadIdx.x & 63;
  const int bb  = blockIdx.x;
  const int xcd = bb & 7;
  const int j   = bb >> 3;                 // 0..511 per XCD
  const int qt  = 63 - (j >> 3);           // LPT: heavy strips dispatch first
  const int bh  = xcd * 8 + (j & 7);       // 8 consecutive heads per XCD
  const int h = bh & 31, b = bh >> 5;
  const int qm = qt * 32;
  const int frow = lane & 15, quad = lane >> 4, fk = quad * 8;

  const ushort* Qb = Q  + (((size_t)b * NH  + h)       * S_LEN + qm) * HD;
  const ushort* Kb = Kk + ((size_t)b * NKV + (h >> 2)) * S_LEN * HD;
  const ushort* Vb = Vt + ((size_t)b * NKV + (h >> 2)) * HD * S_LEN;

  const short8 q00 = *(const short8*)&Qb[frow * HD + fk];
  const short8 q01 = *(const short8*)&Qb[frow * HD + 32 + fk];
  const short8 q10 = *(const short8*)&Qb[(16 + frow) * HD + fk];
  const short8 q11 = *(const short8*)&Qb[(16 + frow) * HD + 32 + fk];

  floatx4 o00 = {}, o01 = {}, o02 = {}, o03 = {};
  floatx4 o10 = {}, o11 = {}, o12 = {}, o13 = {};
  float lp0 = 0.f, lp1 = 0.f;               // per-lane denom partial (q = frow)

  // split-K: tiles [0,Th) -> wave0, [Th,T) -> wave1
  const int T  = qt + 1;
  const int Th = (T + 1) >> 1;
  const int ta = wave ? Th : 0;
  const int tb = wave ? T : Th;
  const int tbu = (tb == T) ? T - 1 : tb;   // end of unmasked region

  short8 kA0, kA1, kA2, kA3, kB0, kB1, kB2, kB3;
  if (ta < tb) {
    const int j0 = ta * 32;
    kA0 = *(const short8*)&Kb[(size_t)(j0 + frow) * HD + fk];
    kA1 = *(const short8*)&Kb[(size_t)(j0 + frow) * HD + 32 + fk];
    kA2 = *(const short8*)&Kb[(size_t)(j0 + 16 + frow) * HD + fk];
    kA3 = *(const short8*)&Kb[(size_t)(j0 + 16 + frow) * HD + 32 + fk];
  }

  int t = ta;
  for (; t + 1 < tbu; t += 2) {
    FA_BODY(kA0, kA1, kA2, kA3, kB0, kB1, kB2, kB3, t, 0);
    FA_BODY(kB0, kB1, kB2, kB3, kA0, kA1, kA2, kA3, t + 1, 0);
  }
  if (t < tbu) {
    FA_BODY(kA0, kA1, kA2, kA3, kB0, kB1, kB2, kB3, t, 0);
    ++t;
    if (t < tb) {   // diagonal tile, buffer parity B
      FA_BODY(kB0, kB1, kB2, kB3, kA0, kA1, kA2, kA3, t, 1);
    }
  } else if (t < tb) {  // diagonal tile, buffer parity A
    FA_BODY(kA0, kA1, kA2, kA3, kB0, kB1, kB2, kB3, t, 1);
  }

  // denom: sum across quads (k-direction), then transpose to O-row layout
  lp0 += __shfl_xor(lp0, 16); lp0 += __shfl_xor(lp0, 32);
  lp1 += __shfl_xor(lp1, 16); lp1 += __shfl_xor(lp1, 32);
  float lpq0[4], lpq1[4];
#pragma unroll
  for (int r = 0; r < 4; ++r) {
    lpq0[r] = __shfl(lp0, quad * 4 + r);   // lanes 0..15 hold full sums
    lpq1[r] = __shfl(lp1, quad * 4 + r);
  }

  // combine wave1's partials into wave0 (stride-33 pad -> conflict-free)
  if (wave == 1) {
#pragma unroll
    for (int r = 0; r < 4; ++r) {
      obuf[lane * 33 +  0 + r] = o00[r];
      obuf[lane * 33 +  4 + r] = o01[r];
      obuf[lane * 33 +  8 + r] = o02[r];
      obuf[lane * 33 + 12 + r] = o03[r];
      obuf[lane * 33 + 16 + r] = o10[r];
      obuf[lane * 33 + 20 + r] = o11[r];
      obuf[lane * 33 + 24 + r] = o12[r];
      obuf[lane * 33 + 28 + r] = o13[r];
      lpbuf[lane * 8 + r]     = lpq0[r];
      lpbuf[lane * 8 + 4 + r] = lpq1[r];
    }
  }
  __syncthreads();
  if (wave != 0) return;

#pragma unroll
  for (int r = 0; r < 4; ++r) {
    o00[r] += obuf[lane * 33 +  0 + r];
    o01[r] += obuf[lane * 33 +  4 + r];
    o02[r] += obuf[lane * 33 +  8 + r];
    o03[r] += obuf[lane * 33 + 12 + r];
    o10[r] += obuf[lane * 33 + 16 + r];
    o11[r] += obuf[lane * 33 + 20 + r];
    o12[r] += obuf[lane * 33 + 24 + r];
    o13[r] += obuf[lane * 33 + 28 + r];
    lpq0[r] += lpbuf[lane * 8 + r];
    lpq1[r] += lpbuf[lane * 8 + 4 + r];
  }

  const size_t obase = ((size_t)b * S_LEN + qm) * HID + (size_t)h * HD;
#pragma unroll
  for (int r = 0; r < 4; ++r) {
    const float i0 = 1.0f / lpq0[r];
    const float i1 = 1.0f / lpq1[r];
    const size_t r0 = obase + (size_t)(quad * 4 + r) * HID;
    const size_t r1 = obase + (size_t)(16 + quad * 4 + r) * HID;
    O[r0 +  0 + frow] = f2bf(o00[r] * i0);
    O[r0 + 16 + frow] = f2bf(o01[r] * i0);
    O[r0 + 32 + frow] = f2bf(o02[r] * i0);
    O[r0 + 48 + frow] = f2bf(o03[r] * i0);
    O[r1 +  0 + frow] = f2bf(o10[r] * i1);
    O[r1 + 16 + frow] = f2bf(o11[r] * i1);
    O[r1 + 32 + frow] = f2bf(o12[r] * i1);
    O[r1 + 48 + frow] = f2bf(o13[r] * i1);
  }
}

// ---------------------------------------------------------------------------
// Workspace layout — 60 MiB:
//   R0 @ 0        (16 MiB): hb (hidden bf16) -> Q  (after gemm1)
//   R1 @ 16 MiB   (12 MiB): wq (w_qkv bf16)  -> wo (after gemm1)
//   R2 @ 28 MiB   (24 MiB): qkv              -> O  (after ln_rope)
//   R3 @ 52 MiB   ( 4 MiB): K
//   R4 @ 56 MiB   ( 4 MiB): Vt
// Output: fp32, written directly by gemm_nt<false>.
// ---------------------------------------------------------------------------
extern "C" void kernel_launch(void* const* d_in, const int* in_sizes, int n_in,
                              void* d_out, int out_size, void* d_ws, size_t ws_size,
                              hipStream_t stream) {
  (void)in_sizes; (void)n_in; (void)out_size; (void)ws_size;
  const int*   pos    = (const int*)d_in[0];
  const float* hidden = (const float*)d_in[1];
  const float* w_qkv  = (const float*)d_in[2];
  const float* q_ln_w = (const float*)d_in[3];
  const float* k_ln_w = (const float*)d_in[4];
  const float* w_o    = (const float*)d_in[5];

  char* ws = (char*)d_ws;
  ushort* hb  = (ushort*)(ws);
  ushort* Q   = (ushort*)(ws);                   // reuse R0
  ushort* wq  = (ushort*)(ws + 16777216);
  ushort* wo  = (ushort*)(ws + 16777216);        // reuse R1
  ushort* qkv = (ushort*)(ws + 29360128);
  ushort* O   = (ushort*)(ws + 29360128);        // reuse R2
  ushort* Kk  = (ushort*)(ws + 54525952);
  ushort* Vt  = (ushort*)(ws + 58720256);

  cvt_f32_bf16<<<dim3(4096), 256, 0, stream>>>(hidden, hb, 8388608 / 8);
  cvt_f32_bf16<<<dim3(3072), 256, 0, stream>>>(w_qkv, wq, 6291456 / 8);
  gemm_nt<true><<<dim3(QKV_N / 128, ROWS / 128), 256, 0, stream>>>(
      hb, wq, qkv, ROWS, QKV_N, HID);
  ln_rope_split<<<dim3(ROWS * 48 / 4), 256, 0, stream>>>(
      qkv, pos, q_ln_w, k_ln_w, Q, Kk, Vt);
  cvt_f32_bf16<<<dim3(2048), 256, 0, stream>>>(w_o, wo, 4194304 / 8);
  flash_attn<<<dim3(4096), 128, 0, stream>>>(Q, Kk, Vt, O);
  gemm_nt<false><<<dim3(HID / 128, ROWS / 128), 256, 0, stream>>>(
      O, wo, d_out, ROWS, HID, HID);
}

// Round 4
// 424.808 us; speedup vs baseline: 1.1740x; 1.1740x over previous
//
#include <hip/hip_runtime.h>
#include <hip/hip_bf16.h>

#define S_LEN 2048
#define HID   2048
#define NH    32
#define NKV   8
#define HD    64
#define ROT   16
#define QKV_N 3072
#define ROWS  4096   // B*S

typedef __attribute__((ext_vector_type(8))) short short8;
typedef __attribute__((ext_vector_type(8))) unsigned short ushort8;
typedef __attribute__((ext_vector_type(4))) float floatx4;

static __device__ __forceinline__ float bf2f(ushort u) {
  union { unsigned int i; float f; } v; v.i = ((unsigned int)u) << 16; return v.f;
}
static __device__ __forceinline__ ushort f2bf(float f) {
  union { __hip_bfloat16 h; ushort u; } v; v.h = __float2bfloat16(f); return v.u;
}

// ---------------------------------------------------------------------------
// fp32 -> bf16 convert, 8 elems/thread (inputs are fp32)
// ---------------------------------------------------------------------------
__global__ __launch_bounds__(256)
void cvt_f32_bf16(const float* __restrict__ in, ushort* __restrict__ out, int n8) {
  const int i = blockIdx.x * 256 + threadIdx.x;
  if (i >= n8) return;
  const float4 a = ((const float4*)in)[2 * i];
  const float4 b = ((const float4*)in)[2 * i + 1];
  ushort8 o;
  o[0] = f2bf(a.x); o[1] = f2bf(a.y); o[2] = f2bf(a.z); o[3] = f2bf(a.w);
  o[4] = f2bf(b.x); o[5] = f2bf(b.y); o[6] = f2bf(b.z); o[7] = f2bf(b.w);
  ((ushort8*)out)[i] = o;
}

// ---------------------------------------------------------------------------
// NT GEMM (m97 structure): 128x128 tile, BK=32, global_load_lds width-16,
// 4 waves x 4x4 mfma_f32_16x16x32_bf16. OUT_BF16 ? bf16 C : fp32 C.
// ---------------------------------------------------------------------------
template<bool OUT_BF16>
__global__ __launch_bounds__(256, 2)
void gemm_nt(const ushort* __restrict__ A, const ushort* __restrict__ B,
             void* __restrict__ Cout, int M, int N, int K) {
  __shared__ ushort lA[128 * 32];
  __shared__ ushort lB[128 * 32];
  const int tid  = threadIdx.x;
  const int wave = tid >> 6, lane = tid & 63;
  const int wr = (wave >> 1) * 64, wc = (wave & 1) * 64;
  const int frow = lane & 15, quad = lane >> 4;
  const int fk = quad * 8;
  const int srow = lane >> 2, skk = (lane & 3) * 8;
  const size_t bm = (size_t)blockIdx.y * 128;
  const size_t bn = (size_t)blockIdx.x * 128;
  const ushort* Ab = A + bm * K;
  const ushort* Bb = B + bn * K;
  floatx4 acc[4][4] = {};

  for (int k0 = 0; k0 < K; k0 += 32) {
    __syncthreads();
    {
      const int c0 = wave * 2;
      const ushort* ga = Ab + (size_t)(c0 * 16 + srow) * K + (k0 + skk);
      const ushort* gb = Bb + (size_t)(c0 * 16 + srow) * K + (k0 + skk);
      __builtin_amdgcn_global_load_lds((const __attribute__((address_space(1))) void*)ga,
          (__attribute__((address_space(3))) void*)&lA[c0 * 512], 16, 0, 0);
      __builtin_amdgcn_global_load_lds((const __attribute__((address_space(1))) void*)gb,
          (__attribute__((address_space(3))) void*)&lB[c0 * 512], 16, 0, 0);
      __builtin_amdgcn_global_load_lds((const __attribute__((address_space(1))) void*)(ga + (size_t)16 * K),
          (__attribute__((address_space(3))) void*)&lA[(c0 + 1) * 512], 16, 0, 0);
      __builtin_amdgcn_global_load_lds((const __attribute__((address_space(1))) void*)(gb + (size_t)16 * K),
          (__attribute__((address_space(3))) void*)&lB[(c0 + 1) * 512], 16, 0, 0);
    }
    __syncthreads();

    short8 af[4], bfr[4];
#pragma unroll
    for (int i = 0; i < 4; ++i)
      af[i] = *(const short8*)&lA[(wr + i * 16 + frow) * 32 + fk];
#pragma unroll
    for (int i = 0; i < 4; ++i)
      bfr[i] = *(const short8*)&lB[(wc + i * 16 + frow) * 32 + fk];
#pragma unroll
    for (int i = 0; i < 4; ++i)
#pragma unroll
      for (int j = 0; j < 4; ++j)
        acc[i][j] = __builtin_amdgcn_mfma_f32_16x16x32_bf16(af[i], bfr[j], acc[i][j], 0, 0, 0);
  }

  const int r0 = quad * 4;
#pragma unroll
  for (int i = 0; i < 4; ++i) {
#pragma unroll
    for (int r = 0; r < 4; ++r) {
      const size_t row = bm + wr + i * 16 + r0 + r;
#pragma unroll
      for (int j = 0; j < 4; ++j) {
        const size_t col = bn + wc + j * 16 + frow;
        if (OUT_BF16) ((ushort*)Cout)[row * N + col] = f2bf(acc[i][j][r]);
        else          ((float*)Cout)[row * N + col] = acc[i][j][r];
      }
    }
  }
}

// ---------------------------------------------------------------------------
// Per-head LayerNorm + partial NeoX RoPE + split. One wave per (row, slot).
// slot 0..31 = q, 32..39 = k, 40..47 = v. LN weights fp32.
// Q -> (b,h,s,d); K -> (b,kv,s,d); V -> (b,kv,d,s) transposed for flash.
// ---------------------------------------------------------------------------
__global__ __launch_bounds__(256)
void ln_rope_split(const ushort* __restrict__ qkv, const int* __restrict__ pos_ids,
                   const float* __restrict__ qw, const float* __restrict__ kw,
                   ushort* __restrict__ Q, ushort* __restrict__ Kk, ushort* __restrict__ Vt) {
  const int gw   = (blockIdx.x * 256 + threadIdx.x) >> 6;
  const int lane = threadIdx.x & 63;
  const int row  = gw / 48;
  const int slot = gw - row * 48;
  const int b = row >> 11, s = row & 2047;
  const float x = bf2f(qkv[(size_t)row * QKV_N + slot * 64 + lane]);

  if (slot < 40) {
    float s1 = x, s2 = x * x;
#pragma unroll
    for (int d = 1; d < 64; d <<= 1) { s1 += __shfl_xor(s1, d); s2 += __shfl_xor(s2, d); }
    const float mu  = s1 * (1.0f / 64.0f);
    const float var = s2 * (1.0f / 64.0f) - mu * mu;
    const float w = (slot < 32) ? qw[slot * 64 + lane] : kw[(slot - 32) * 64 + lane];
    float y = (x - mu) * rsqrtf(var + 1e-5f) * w;
    if (lane < ROT) {
      const int dd = lane & 7;
      const float invf = powf(10000.0f, -(float)dd * 0.125f);
      const float fr = (float)pos_ids[row] * invf;
      const float c = cosf(fr), sn = sinf(fr);
      const float yp = __shfl_xor(y, 8);
      y = (lane < 8) ? (y * c - yp * sn) : (y * c + yp * sn);
    }
    if (slot < 32)
      Q[(((size_t)b * NH + slot) * S_LEN + s) * HD + lane] = f2bf(y);
    else
      Kk[(((size_t)b * NKV + (slot - 32)) * S_LEN + s) * HD + lane] = f2bf(y);
  } else {
    const int kvh = slot - 40;
    Vt[(((size_t)b * NKV + kvh) * HD + lane) * S_LEN + s] = f2bf(x);
  }
}

// ---------------------------------------------------------------------------
// Causal GQA flash attention, FIXED-CAP softmax (no online rescaling):
// LayerNorm bounds |q|,|k| <= 8 -> s = q.k/8 in [-8.1,8.1]; p = exp(s - 9)
// cannot overflow; softmax shift-invariance makes it exact.
//
// v5 = v4 structure with the spill fixed. v4's __launch_bounds__(128,4)
// capped VGPR at 128 < ~190 live set -> accumulators spilled to scratch
// (WRITE_SIZE 26->426 MB, kernel became spill-BW-bound at 2.37 TB/s).
// (128,2) caps at 256: fits with headroom, >=2 waves/SIMD, zero scratch.
//  * Swapped QK^T: S^T = mfma(K, Q); softmax denom lane-local.
//  * In-register P regroup: 4x v_cvt_pk_bf16_f32 + 8 shfl + 4 cndmask;
//    PV = mfma(pfrag, v). No P LDS, no barriers, no lgkmcnt drains.
//  * Diagonal-only masking; split-K 2-wave blocks + additive combine;
//    LPT grid; XCD-locality remap; K reg dbuf; V issue-early/use-late.
// ---------------------------------------------------------------------------
#define SMAX 9.0f

// Regroup P from S^T-accumulator layout (q=frow, k=quad*4+r; pa=k 0..15,
// pb=k 16..31) into the PV A-operand layout (q=frow, k=quad*8+0..7).
static __device__ __forceinline__ short8 build_pfrag(floatx4 pa, floatx4 pb,
                                                     int frow, int quad) {
  int w0, w1, w2, w3;
  asm("v_cvt_pk_bf16_f32 %0, %1, %2" : "=v"(w0) : "v"(pa[0]), "v"(pa[1]));
  asm("v_cvt_pk_bf16_f32 %0, %1, %2" : "=v"(w1) : "v"(pa[2]), "v"(pa[3]));
  asm("v_cvt_pk_bf16_f32 %0, %1, %2" : "=v"(w2) : "v"(pb[0]), "v"(pb[1]));
  asm("v_cvt_pk_bf16_f32 %0, %1, %2" : "=v"(w3) : "v"(pb[2]), "v"(pb[3]));
  const int sA = frow + ((quad & 1) << 5);   // src quad 0 or 2
  const int sB = sA + 16;                    // src quad 1 or 3
  const int t0 = __shfl(w0, sA), t1 = __shfl(w1, sA);
  const int t2 = __shfl(w0, sB), t3 = __shfl(w1, sB);
  const int u0 = __shfl(w2, sA), u1 = __shfl(w3, sA);
  const int u2 = __shfl(w2, sB), u3 = __shfl(w3, sB);
  const bool lo = quad < 2;                  // k<16 half vs k>=16 half
  union { int i[4]; short8 s; } r;
  r.i[0] = lo ? t0 : u0;
  r.i[1] = lo ? t1 : u1;
  r.i[2] = lo ? t2 : u2;
  r.i[3] = lo ? t3 : u3;
  return r.s;
}

#define FA_BODY(KC0,KC1,KC2,KC3, KN0,KN1,KN2,KN3, TI, MASKED)                  \
  {                                                                            \
    const int jj = (TI) * 32;                                                  \
    const short8 v0 = *(const short8*)&Vb[(size_t)( 0 + frow) * S_LEN + jj + fk]; \
    const short8 v1 = *(const short8*)&Vb[(size_t)(16 + frow) * S_LEN + jj + fk]; \
    const short8 v2 = *(const short8*)&Vb[(size_t)(32 + frow) * S_LEN + jj + fk]; \
    const short8 v3 = *(const short8*)&Vb[(size_t)(48 + frow) * S_LEN + jj + fk]; \
    const floatx4 z = {};                                                      \
    floatx4 st00 = __builtin_amdgcn_mfma_f32_16x16x32_bf16(KC0, q00, z, 0, 0, 0); \
    st00 = __builtin_amdgcn_mfma_f32_16x16x32_bf16(KC1, q01, st00, 0, 0, 0);   \
    floatx4 st01 = __builtin_amdgcn_mfma_f32_16x16x32_bf16(KC2, q00, z, 0, 0, 0); \
    st01 = __builtin_amdgcn_mfma_f32_16x16x32_bf16(KC3, q01, st01, 0, 0, 0);   \
    floatx4 st10 = __builtin_amdgcn_mfma_f32_16x16x32_bf16(KC0, q10, z, 0, 0, 0); \
    st10 = __builtin_amdgcn_mfma_f32_16x16x32_bf16(KC1, q11, st10, 0, 0, 0);   \
    floatx4 st11 = __builtin_amdgcn_mfma_f32_16x16x32_bf16(KC2, q10, z, 0, 0, 0); \
    st11 = __builtin_amdgcn_mfma_f32_16x16x32_bf16(KC3, q11, st11, 0, 0, 0);   \
    if ((TI) + 1 < tb) {                                                       \
      const int jn = ((TI) + 1) * 32;                                          \
      KN0 = *(const short8*)&Kb[(size_t)(jn + frow) * HD + fk];                \
      KN1 = *(const short8*)&Kb[(size_t)(jn + frow) * HD + 32 + fk];           \
      KN2 = *(const short8*)&Kb[(size_t)(jn + 16 + frow) * HD + fk];           \
      KN3 = *(const short8*)&Kb[(size_t)(jn + 16 + frow) * HD + 32 + fk];      \
    }                                                                          \
    floatx4 p00, p01, p10, p11;                                                \
    _Pragma("unroll")                                                          \
    for (int r = 0; r < 4; ++r) {                                              \
      if (MASKED) {                                                            \
        const int kg0 = jj + quad * 4 + r;                                     \
        const int kg1 = kg0 + 16;                                              \
        p00[r] = (kg0 <= qm + frow)      ? __expf(st00[r] * 0.125f - SMAX) : 0.0f; \
        p01[r] = (kg1 <= qm + frow)      ? __expf(st01[r] * 0.125f - SMAX) : 0.0f; \
        p10[r] = (kg0 <= qm + 16 + frow) ? __expf(st10[r] * 0.125f - SMAX) : 0.0f; \
        p11[r] = (kg1 <= qm + 16 + frow) ? __expf(st11[r] * 0.125f - SMAX) : 0.0f; \
      } else {                                                                 \
        p00[r] = __expf(st00[r] * 0.125f - SMAX);                              \
        p01[r] = __expf(st01[r] * 0.125f - SMAX);                              \
        p10[r] = __expf(st10[r] * 0.125f - SMAX);                              \
        p11[r] = __expf(st11[r] * 0.125f - SMAX);                              \
      }                                                                        \
      lp0 += p00[r] + p01[r];                                                  \
      lp1 += p10[r] + p11[r];                                                  \
    }                                                                          \
    const short8 pf0 = build_pfrag(p00, p01, frow, quad);                      \
    const short8 pf1 = build_pfrag(p10, p11, frow, quad);                      \
    o00 = __builtin_amdgcn_mfma_f32_16x16x32_bf16(pf0, v0, o00, 0, 0, 0);      \
    o01 = __builtin_amdgcn_mfma_f32_16x16x32_bf16(pf0, v1, o01, 0, 0, 0);      \
    o02 = __builtin_amdgcn_mfma_f32_16x16x32_bf16(pf0, v2, o02, 0, 0, 0);      \
    o03 = __builtin_amdgcn_mfma_f32_16x16x32_bf16(pf0, v3, o03, 0, 0, 0);      \
    o10 = __builtin_amdgcn_mfma_f32_16x16x32_bf16(pf1, v0, o10, 0, 0, 0);      \
    o11 = __builtin_amdgcn_mfma_f32_16x16x32_bf16(pf1, v1, o11, 0, 0, 0);      \
    o12 = __builtin_amdgcn_mfma_f32_16x16x32_bf16(pf1, v2, o12, 0, 0, 0);      \
    o13 = __builtin_amdgcn_mfma_f32_16x16x32_bf16(pf1, v3, o13, 0, 0, 0);      \
  }

__global__ __launch_bounds__(128, 2)
void flash_attn(const ushort* __restrict__ Q, const ushort* __restrict__ Kk,
                const ushort* __restrict__ Vt, ushort* __restrict__ O) {
  __shared__ float obuf[64 * 33];
  __shared__ float lpbuf[64 * 8];
  const int wave = threadIdx.x >> 6, lane = threadIdx.x & 63;
  const int bb  = blockIdx.x;
  const int xcd = bb & 7;
  const int j   = bb >> 3;                 // 0..511 per XCD
  const int qt  = 63 - (j >> 3);           // LPT: heavy strips dispatch first
  const int bh  = xcd * 8 + (j & 7);       // 8 consecutive heads per XCD
  const int h = bh & 31, b = bh >> 5;
  const int qm = qt * 32;
  const int frow = lane & 15, quad = lane >> 4, fk = quad * 8;

  const ushort* Qb = Q  + (((size_t)b * NH  + h)       * S_LEN + qm) * HD;
  const ushort* Kb = Kk + ((size_t)b * NKV + (h >> 2)) * S_LEN * HD;
  const ushort* Vb = Vt + ((size_t)b * NKV + (h >> 2)) * HD * S_LEN;

  const short8 q00 = *(const short8*)&Qb[frow * HD + fk];
  const short8 q01 = *(const short8*)&Qb[frow * HD + 32 + fk];
  const short8 q10 = *(const short8*)&Qb[(16 + frow) * HD + fk];
  const short8 q11 = *(const short8*)&Qb[(16 + frow) * HD + 32 + fk];

  floatx4 o00 = {}, o01 = {}, o02 = {}, o03 = {};
  floatx4 o10 = {}, o11 = {}, o12 = {}, o13 = {};
  float lp0 = 0.f, lp1 = 0.f;               // per-lane denom partial (q = frow)

  // split-K: tiles [0,Th) -> wave0, [Th,T) -> wave1
  const int T  = qt + 1;
  const int Th = (T + 1) >> 1;
  const int ta = wave ? Th : 0;
  const int tb = wave ? T : Th;
  const int tbu = (tb == T) ? T - 1 : tb;   // end of unmasked region

  short8 kA0, kA1, kA2, kA3, kB0, kB1, kB2, kB3;
  if (ta < tb) {
    const int j0 = ta * 32;
    kA0 = *(const short8*)&Kb[(size_t)(j0 + frow) * HD + fk];
    kA1 = *(const short8*)&Kb[(size_t)(j0 + frow) * HD + 32 + fk];
    kA2 = *(const short8*)&Kb[(size_t)(j0 + 16 + frow) * HD + fk];
    kA3 = *(const short8*)&Kb[(size_t)(j0 + 16 + frow) * HD + 32 + fk];
  }

  int t = ta;
  for (; t + 1 < tbu; t += 2) {
    FA_BODY(kA0, kA1, kA2, kA3, kB0, kB1, kB2, kB3, t, 0);
    FA_BODY(kB0, kB1, kB2, kB3, kA0, kA1, kA2, kA3, t + 1, 0);
  }
  if (t < tbu) {
    FA_BODY(kA0, kA1, kA2, kA3, kB0, kB1, kB2, kB3, t, 0);
    ++t;
    if (t < tb) {   // diagonal tile, buffer parity B
      FA_BODY(kB0, kB1, kB2, kB3, kA0, kA1, kA2, kA3, t, 1);
    }
  } else if (t < tb) {  // diagonal tile, buffer parity A
    FA_BODY(kA0, kA1, kA2, kA3, kB0, kB1, kB2, kB3, t, 1);
  }

  // denom: sum across quads (k-direction), then transpose to O-row layout
  lp0 += __shfl_xor(lp0, 16); lp0 += __shfl_xor(lp0, 32);
  lp1 += __shfl_xor(lp1, 16); lp1 += __shfl_xor(lp1, 32);
  float lpq0[4], lpq1[4];
#pragma unroll
  for (int r = 0; r < 4; ++r) {
    lpq0[r] = __shfl(lp0, quad * 4 + r);   // lanes 0..15 hold full sums
    lpq1[r] = __shfl(lp1, quad * 4 + r);
  }

  // combine wave1's partials into wave0 (stride-33 pad -> conflict-free)
  if (wave == 1) {
#pragma unroll
    for (int r = 0; r < 4; ++r) {
      obuf[lane * 33 +  0 + r] = o00[r];
      obuf[lane * 33 +  4 + r] = o01[r];
      obuf[lane * 33 +  8 + r] = o02[r];
      obuf[lane * 33 + 12 + r] = o03[r];
      obuf[lane * 33 + 16 + r] = o10[r];
      obuf[lane * 33 + 20 + r] = o11[r];
      obuf[lane * 33 + 24 + r] = o12[r];
      obuf[lane * 33 + 28 + r] = o13[r];
      lpbuf[lane * 8 + r]     = lpq0[r];
      lpbuf[lane * 8 + 4 + r] = lpq1[r];
    }
  }
  __syncthreads();
  if (wave != 0) return;

#pragma unroll
  for (int r = 0; r < 4; ++r) {
    o00[r] += obuf[lane * 33 +  0 + r];
    o01[r] += obuf[lane * 33 +  4 + r];
    o02[r] += obuf[lane * 33 +  8 + r];
    o03[r] += obuf[lane * 33 + 12 + r];
    o10[r] += obuf[lane * 33 + 16 + r];
    o11[r] += obuf[lane * 33 + 20 + r];
    o12[r] += obuf[lane * 33 + 24 + r];
    o13[r] += obuf[lane * 33 + 28 + r];
    lpq0[r] += lpbuf[lane * 8 + r];
    lpq1[r] += lpbuf[lane * 8 + 4 + r];
  }

  const size_t obase = ((size_t)b * S_LEN + qm) * HID + (size_t)h * HD;
#pragma unroll
  for (int r = 0; r < 4; ++r) {
    const float i0 = 1.0f / lpq0[r];
    const float i1 = 1.0f / lpq1[r];
    const size_t r0 = obase + (size_t)(quad * 4 + r) * HID;
    const size_t r1 = obase + (size_t)(16 + quad * 4 + r) * HID;
    O[r0 +  0 + frow] = f2bf(o00[r] * i0);
    O[r0 + 16 + frow] = f2bf(o01[r] * i0);
    O[r0 + 32 + frow] = f2bf(o02[r] * i0);
    O[r0 + 48 + frow] = f2bf(o03[r] * i0);
    O[r1 +  0 + frow] = f2bf(o10[r] * i1);
    O[r1 + 16 + frow] = f2bf(o11[r] * i1);
    O[r1 + 32 + frow] = f2bf(o12[r] * i1);
    O[r1 + 48 + frow] = f2bf(o13[r] * i1);
  }
}

// ---------------------------------------------------------------------------
// Workspace layout — 60 MiB:
//   R0 @ 0        (16 MiB): hb (hidden bf16) -> Q  (after gemm1)
//   R1 @ 16 MiB   (12 MiB): wq (w_qkv bf16)  -> wo (after gemm1)
//   R2 @ 28 MiB   (24 MiB): qkv              -> O  (after ln_rope)
//   R3 @ 52 MiB   ( 4 MiB): K
//   R4 @ 56 MiB   ( 4 MiB): Vt
// Output: fp32, written directly by gemm_nt<false>.
// ---------------------------------------------------------------------------
extern "C" void kernel_launch(void* const* d_in, const int* in_sizes, int n_in,
                              void* d_out, int out_size, void* d_ws, size_t ws_size,
                              hipStream_t stream) {
  (void)in_sizes; (void)n_in; (void)out_size; (void)ws_size;
  const int*   pos    = (const int*)d_in[0];
  const float* hidden = (const float*)d_in[1];
  const float* w_qkv  = (const float*)d_in[2];
  const float* q_ln_w = (const float*)d_in[3];
  const float* k_ln_w = (const float*)d_in[4];
  const float* w_o    = (const float*)d_in[5];

  char* ws = (char*)d_ws;
  ushort* hb  = (ushort*)(ws);
  ushort* Q   = (ushort*)(ws);                   // reuse R0
  ushort* wq  = (ushort*)(ws + 16777216);
  ushort* wo  = (ushort*)(ws + 16777216);        // reuse R1
  ushort* qkv = (ushort*)(ws + 29360128);
  ushort* O   = (ushort*)(ws + 29360128);        // reuse R2
  ushort* Kk  = (ushort*)(ws + 54525952);
  ushort* Vt  = (ushort*)(ws + 58720256);

  cvt_f32_bf16<<<dim3(4096), 256, 0, stream>>>(hidden, hb, 8388608 / 8);
  cvt_f32_bf16<<<dim3(3072), 256, 0, stream>>>(w_qkv, wq, 6291456 / 8);
  gemm_nt<true><<<dim3(QKV_N / 128, ROWS / 128), 256, 0, stream>>>(
      hb, wq, qkv, ROWS, QKV_N, HID);
  ln_rope_split<<<dim3(ROWS * 48 / 4), 256, 0, stream>>>(
      qkv, pos, q_ln_w, k_ln_w, Q, Kk, Vt);
  cvt_f32_bf16<<<dim3(2048), 256, 0, stream>>>(w_o, wo, 4194304 / 8);
  flash_attn<<<dim3(4096), 128, 0, stream>>>(Q, Kk, Vt, O);
  gemm_nt<false><<<dim3(HID / 128, ROWS / 128), 256, 0, stream>>>(
      O, wo, d_out, ROWS, HID, HID);
}

// Round 6
// 424.648 us; speedup vs baseline: 1.1745x; 1.0004x over previous
//
#include <hip/hip_runtime.h>
#include <hip/hip_bf16.h>

#define S_LEN 2048
#define HID   2048
#define NH    32
#define NKV   8
#define HD    64
#define ROT   16
#define QKV_N 3072
#define ROWS  4096   // B*S

typedef __attribute__((ext_vector_type(8))) short short8;
typedef __attribute__((ext_vector_type(8))) unsigned short ushort8;
typedef __attribute__((ext_vector_type(4))) float floatx4;

static __device__ __forceinline__ float bf2f(ushort u) {
  union { unsigned int i; float f; } v; v.i = ((unsigned int)u) << 16; return v.f;
}
static __device__ __forceinline__ ushort f2bf(float f) {
  union { __hip_bfloat16 h; ushort u; } v; v.h = __float2bfloat16(f); return v.u;
}

// ---------------------------------------------------------------------------
// fp32 -> bf16 convert, 8 elems/thread (inputs are fp32)
// ---------------------------------------------------------------------------
__global__ __launch_bounds__(256)
void cvt_f32_bf16(const float* __restrict__ in, ushort* __restrict__ out, int n8) {
  const int i = blockIdx.x * 256 + threadIdx.x;
  if (i >= n8) return;
  const float4 a = ((const float4*)in)[2 * i];
  const float4 b = ((const float4*)in)[2 * i + 1];
  ushort8 o;
  o[0] = f2bf(a.x); o[1] = f2bf(a.y); o[2] = f2bf(a.z); o[3] = f2bf(a.w);
  o[4] = f2bf(b.x); o[5] = f2bf(b.y); o[6] = f2bf(b.z); o[7] = f2bf(b.w);
  ((ushort8*)out)[i] = o;
}

// ---------------------------------------------------------------------------
// NT GEMM (m97 structure): 128x128 tile, BK=32, global_load_lds width-16,
// 4 waves x 4x4 mfma_f32_16x16x32_bf16. OUT_BF16 ? bf16 C : fp32 C.
// v7: + XCD-bijective block swizzle (T1). nwg%8==0 for both shapes
// (768, 512) -> swz=(lin&7)*cpx+(lin>>3) is bijective; each XCD gets a
// contiguous run of output tiles sharing A-panels (~2MB, L2-resident).
// ---------------------------------------------------------------------------
template<bool OUT_BF16>
__global__ __launch_bounds__(256, 2)
void gemm_nt(const ushort* __restrict__ A, const ushort* __restrict__ B,
             void* __restrict__ Cout, int M, int N, int K) {
  __shared__ ushort lA[128 * 32];
  __shared__ ushort lB[128 * 32];
  const int tid  = threadIdx.x;
  const int wave = tid >> 6, lane = tid & 63;
  const int wr = (wave >> 1) * 64, wc = (wave & 1) * 64;
  const int frow = lane & 15, quad = lane >> 4;
  const int fk = quad * 8;
  const int srow = lane >> 2, skk = (lane & 3) * 8;

  // XCD-bijective swizzle of the linear block id
  const int gx  = gridDim.x;
  const int nwg = gx * gridDim.y;
  const int lin = blockIdx.y * gx + blockIdx.x;
  const int cpx = nwg >> 3;
  const int swz = (lin & 7) * cpx + (lin >> 3);
  const int bxi = swz % gx, byi = swz / gx;

  const size_t bm = (size_t)byi * 128;
  const size_t bn = (size_t)bxi * 128;
  const ushort* Ab = A + bm * K;
  const ushort* Bb = B + bn * K;
  floatx4 acc[4][4] = {};

  for (int k0 = 0; k0 < K; k0 += 32) {
    __syncthreads();
    {
      const int c0 = wave * 2;
      const ushort* ga = Ab + (size_t)(c0 * 16 + srow) * K + (k0 + skk);
      const ushort* gb = Bb + (size_t)(c0 * 16 + srow) * K + (k0 + skk);
      __builtin_amdgcn_global_load_lds((const __attribute__((address_space(1))) void*)ga,
          (__attribute__((address_space(3))) void*)&lA[c0 * 512], 16, 0, 0);
      __builtin_amdgcn_global_load_lds((const __attribute__((address_space(1))) void*)gb,
          (__attribute__((address_space(3))) void*)&lB[c0 * 512], 16, 0, 0);
      __builtin_amdgcn_global_load_lds((const __attribute__((address_space(1))) void*)(ga + (size_t)16 * K),
          (__attribute__((address_space(3))) void*)&lA[(c0 + 1) * 512], 16, 0, 0);
      __builtin_amdgcn_global_load_lds((const __attribute__((address_space(1))) void*)(gb + (size_t)16 * K),
          (__attribute__((address_space(3))) void*)&lB[(c0 + 1) * 512], 16, 0, 0);
    }
    __syncthreads();

    short8 af[4], bfr[4];
#pragma unroll
    for (int i = 0; i < 4; ++i)
      af[i] = *(const short8*)&lA[(wr + i * 16 + frow) * 32 + fk];
#pragma unroll
    for (int i = 0; i < 4; ++i)
      bfr[i] = *(const short8*)&lB[(wc + i * 16 + frow) * 32 + fk];
#pragma unroll
    for (int i = 0; i < 4; ++i)
#pragma unroll
      for (int j = 0; j < 4; ++j)
        acc[i][j] = __builtin_amdgcn_mfma_f32_16x16x32_bf16(af[i], bfr[j], acc[i][j], 0, 0, 0);
  }

  const int r0 = quad * 4;
#pragma unroll
  for (int i = 0; i < 4; ++i) {
#pragma unroll
    for (int r = 0; r < 4; ++r) {
      const size_t row = bm + wr + i * 16 + r0 + r;
#pragma unroll
      for (int j = 0; j < 4; ++j) {
        const size_t col = bn + wc + j * 16 + frow;
        if (OUT_BF16) ((ushort*)Cout)[row * N + col] = f2bf(acc[i][j][r]);
        else          ((float*)Cout)[row * N + col] = acc[i][j][r];
      }
    }
  }
}

// ---------------------------------------------------------------------------
// Per-head LayerNorm + partial NeoX RoPE + split. One wave per (row, slot).
// slot 0..31 = q, 32..39 = k, 40..47 = v. LN weights fp32.
// Q -> (b,h,s,d); K -> (b,kv,s,d); V -> (b,kv,d,s) transposed for flash.
// ---------------------------------------------------------------------------
__global__ __launch_bounds__(256)
void ln_rope_split(const ushort* __restrict__ qkv, const int* __restrict__ pos_ids,
                   const float* __restrict__ qw, const float* __restrict__ kw,
                   ushort* __restrict__ Q, ushort* __restrict__ Kk, ushort* __restrict__ Vt) {
  const int gw   = (blockIdx.x * 256 + threadIdx.x) >> 6;
  const int lane = threadIdx.x & 63;
  const int row  = gw / 48;
  const int slot = gw - row * 48;
  const int b = row >> 11, s = row & 2047;
  const float x = bf2f(qkv[(size_t)row * QKV_N + slot * 64 + lane]);

  if (slot < 40) {
    float s1 = x, s2 = x * x;
#pragma unroll
    for (int d = 1; d < 64; d <<= 1) { s1 += __shfl_xor(s1, d); s2 += __shfl_xor(s2, d); }
    const float mu  = s1 * (1.0f / 64.0f);
    const float var = s2 * (1.0f / 64.0f) - mu * mu;
    const float w = (slot < 32) ? qw[slot * 64 + lane] : kw[(slot - 32) * 64 + lane];
    float y = (x - mu) * rsqrtf(var + 1e-5f) * w;
    if (lane < ROT) {
      const int dd = lane & 7;
      const float invf = powf(10000.0f, -(float)dd * 0.125f);
      const float fr = (float)pos_ids[row] * invf;
      const float c = cosf(fr), sn = sinf(fr);
      const float yp = __shfl_xor(y, 8);
      y = (lane < 8) ? (y * c - yp * sn) : (y * c + yp * sn);
    }
    if (slot < 32)
      Q[(((size_t)b * NH + slot) * S_LEN + s) * HD + lane] = f2bf(y);
    else
      Kk[(((size_t)b * NKV + (slot - 32)) * S_LEN + s) * HD + lane] = f2bf(y);
  } else {
    const int kvh = slot - 40;
    Vt[(((size_t)b * NKV + kvh) * HD + lane) * S_LEN + s] = f2bf(x);
  }
}

// ---------------------------------------------------------------------------
// Causal GQA flash attention, FIXED-CAP softmax (no online rescaling):
// LayerNorm bounds |q|,|k| <= 8 -> s = q.k/8 in [-8.1,8.1]; p = exp(s - 9)
// cannot overflow; softmax shift-invariance makes it exact.
//
// v7 = v5 body, decoupled waves, compiled in v5's EXACT regime.
// v6 (64-thread blocks, __launch_bounds__(64,3) -> VGPR cap 168, at the
// edge of the ~160-reg live set) failed correctness; the math was verified
// identical to v5, so the suspect is the at-cap allocation regime. v7 keeps
// 128-thread blocks + (128,2) (cap 256, v5-identical codegen regime) but
// the two waves own two INDEPENDENT strips: same head (shared K/V in
// L1/L2), adjacent qt (retirement skew ~1 tile). No LDS, no barriers, no
// combine. Each wave: full causal K range for its strip.
//  * Swapped QK^T: S^T = mfma(K, Q); softmax denom lane-local.
//  * In-register P regroup: 4x v_cvt_pk_bf16_f32 + 8 shfl + 4 cndmask;
//    PV = mfma(pfrag, v). No P LDS, no lgkmcnt drains.
//  * Diagonal-only masking; K reg dbuf; V issue-early/use-late.
//  * LPT: qt descending in dispatch order; XCD-bijective head mapping.
// ---------------------------------------------------------------------------
#define SMAX 9.0f

// Regroup P from S^T-accumulator layout (q=frow, k=quad*4+r; pa=k 0..15,
// pb=k 16..31) into the PV A-operand layout (q=frow, k=quad*8+0..7).
static __device__ __forceinline__ short8 build_pfrag(floatx4 pa, floatx4 pb,
                                                     int frow, int quad) {
  int w0, w1, w2, w3;
  asm("v_cvt_pk_bf16_f32 %0, %1, %2" : "=v"(w0) : "v"(pa[0]), "v"(pa[1]));
  asm("v_cvt_pk_bf16_f32 %0, %1, %2" : "=v"(w1) : "v"(pa[2]), "v"(pa[3]));
  asm("v_cvt_pk_bf16_f32 %0, %1, %2" : "=v"(w2) : "v"(pb[0]), "v"(pb[1]));
  asm("v_cvt_pk_bf16_f32 %0, %1, %2" : "=v"(w3) : "v"(pb[2]), "v"(pb[3]));
  const int sA = frow + ((quad & 1) << 5);   // src quad 0 or 2
  const int sB = sA + 16;                    // src quad 1 or 3
  const int t0 = __shfl(w0, sA), t1 = __shfl(w1, sA);
  const int t2 = __shfl(w0, sB), t3 = __shfl(w1, sB);
  const int u0 = __shfl(w2, sA), u1 = __shfl(w3, sA);
  const int u2 = __shfl(w2, sB), u3 = __shfl(w3, sB);
  const bool lo = quad < 2;                  // k<16 half vs k>=16 half
  union { int i[4]; short8 s; } r;
  r.i[0] = lo ? t0 : u0;
  r.i[1] = lo ? t1 : u1;
  r.i[2] = lo ? t2 : u2;
  r.i[3] = lo ? t3 : u3;
  return r.s;
}

#define FA_BODY(KC0,KC1,KC2,KC3, KN0,KN1,KN2,KN3, TI, MASKED)                  \
  {                                                                            \
    const int jj = (TI) * 32;                                                  \
    const short8 v0 = *(const short8*)&Vb[(size_t)( 0 + frow) * S_LEN + jj + fk]; \
    const short8 v1 = *(const short8*)&Vb[(size_t)(16 + frow) * S_LEN + jj + fk]; \
    const short8 v2 = *(const short8*)&Vb[(size_t)(32 + frow) * S_LEN + jj + fk]; \
    const short8 v3 = *(const short8*)&Vb[(size_t)(48 + frow) * S_LEN + jj + fk]; \
    const floatx4 z = {};                                                      \
    floatx4 st00 = __builtin_amdgcn_mfma_f32_16x16x32_bf16(KC0, q00, z, 0, 0, 0); \
    st00 = __builtin_amdgcn_mfma_f32_16x16x32_bf16(KC1, q01, st00, 0, 0, 0);   \
    floatx4 st01 = __builtin_amdgcn_mfma_f32_16x16x32_bf16(KC2, q00, z, 0, 0, 0); \
    st01 = __builtin_amdgcn_mfma_f32_16x16x32_bf16(KC3, q01, st01, 0, 0, 0);   \
    floatx4 st10 = __builtin_amdgcn_mfma_f32_16x16x32_bf16(KC0, q10, z, 0, 0, 0); \
    st10 = __builtin_amdgcn_mfma_f32_16x16x32_bf16(KC1, q11, st10, 0, 0, 0);   \
    floatx4 st11 = __builtin_amdgcn_mfma_f32_16x16x32_bf16(KC2, q10, z, 0, 0, 0); \
    st11 = __builtin_amdgcn_mfma_f32_16x16x32_bf16(KC3, q11, st11, 0, 0, 0);   \
    if ((TI) + 1 < tb) {                                                       \
      const int jn = ((TI) + 1) * 32;                                          \
      KN0 = *(const short8*)&Kb[(size_t)(jn + frow) * HD + fk];                \
      KN1 = *(const short8*)&Kb[(size_t)(jn + frow) * HD + 32 + fk];           \
      KN2 = *(const short8*)&Kb[(size_t)(jn + 16 + frow) * HD + fk];           \
      KN3 = *(const short8*)&Kb[(size_t)(jn + 16 + frow) * HD + 32 + fk];      \
    }                                                                          \
    floatx4 p00, p01, p10, p11;                                                \
    _Pragma("unroll")                                                          \
    for (int r = 0; r < 4; ++r) {                                              \
      if (MASKED) {                                                            \
        const int kg0 = jj + quad * 4 + r;                                     \
        const int kg1 = kg0 + 16;                                              \
        p00[r] = (kg0 <= qm + frow)      ? __expf(st00[r] * 0.125f - SMAX) : 0.0f; \
        p01[r] = (kg1 <= qm + frow)      ? __expf(st01[r] * 0.125f - SMAX) : 0.0f; \
        p10[r] = (kg0 <= qm + 16 + frow) ? __expf(st10[r] * 0.125f - SMAX) : 0.0f; \
        p11[r] = (kg1 <= qm + 16 + frow) ? __expf(st11[r] * 0.125f - SMAX) : 0.0f; \
      } else {                                                                 \
        p00[r] = __expf(st00[r] * 0.125f - SMAX);                              \
        p01[r] = __expf(st01[r] * 0.125f - SMAX);                              \
        p10[r] = __expf(st10[r] * 0.125f - SMAX);                              \
        p11[r] = __expf(st11[r] * 0.125f - SMAX);                              \
      }                                                                        \
      lp0 += p00[r] + p01[r];                                                  \
      lp1 += p10[r] + p11[r];                                                  \
    }                                                                          \
    const short8 pf0 = build_pfrag(p00, p01, frow, quad);                      \
    const short8 pf1 = build_pfrag(p10, p11, frow, quad);                      \
    o00 = __builtin_amdgcn_mfma_f32_16x16x32_bf16(pf0, v0, o00, 0, 0, 0);      \
    o01 = __builtin_amdgcn_mfma_f32_16x16x32_bf16(pf0, v1, o01, 0, 0, 0);      \
    o02 = __builtin_amdgcn_mfma_f32_16x16x32_bf16(pf0, v2, o02, 0, 0, 0);      \
    o03 = __builtin_amdgcn_mfma_f32_16x16x32_bf16(pf0, v3, o03, 0, 0, 0);      \
    o10 = __builtin_amdgcn_mfma_f32_16x16x32_bf16(pf1, v0, o10, 0, 0, 0);      \
    o11 = __builtin_amdgcn_mfma_f32_16x16x32_bf16(pf1, v1, o11, 0, 0, 0);      \
    o12 = __builtin_amdgcn_mfma_f32_16x16x32_bf16(pf1, v2, o12, 0, 0, 0);      \
    o13 = __builtin_amdgcn_mfma_f32_16x16x32_bf16(pf1, v3, o13, 0, 0, 0);      \
  }

__global__ __launch_bounds__(128, 2)
void flash_attn(const ushort* __restrict__ Q, const ushort* __restrict__ Kk,
                const ushort* __restrict__ Vt, ushort* __restrict__ O) {
  const int wave = threadIdx.x >> 6, lane = threadIdx.x & 63;
  const int bb  = blockIdx.x;
  const int xcd = bb & 7;
  const int j   = bb >> 3;                       // 0..255 per XCD
  const int bh  = xcd * 8 + (j & 7);             // 8 consecutive heads per XCD
  const int qt  = 63 - ((j >> 3) * 2 + wave);    // LPT: heavy strips first;
                                                 // both waves same head, adjacent qt
  const int h = bh & 31, b = bh >> 5;
  const int qm = qt * 32;
  const int frow = lane & 15, quad = lane >> 4, fk = quad * 8;

  const ushort* Qb = Q  + (((size_t)b * NH  + h)       * S_LEN + qm) * HD;
  const ushort* Kb = Kk + ((size_t)b * NKV + (h >> 2)) * S_LEN * HD;
  const ushort* Vb = Vt + ((size_t)b * NKV + (h >> 2)) * HD * S_LEN;

  const short8 q00 = *(const short8*)&Qb[frow * HD + fk];
  const short8 q01 = *(const short8*)&Qb[frow * HD + 32 + fk];
  const short8 q10 = *(const short8*)&Qb[(16 + frow) * HD + fk];
  const short8 q11 = *(const short8*)&Qb[(16 + frow) * HD + 32 + fk];

  floatx4 o00 = {}, o01 = {}, o02 = {}, o03 = {};
  floatx4 o10 = {}, o11 = {}, o12 = {}, o13 = {};
  float lp0 = 0.f, lp1 = 0.f;               // per-lane denom partial (q = frow)

  // full causal K range for this strip; last tile is the masked diagonal
  const int T   = qt + 1;
  const int tb  = T;
  const int tbu = T - 1;                    // end of unmasked region

  short8 kA0, kA1, kA2, kA3, kB0, kB1, kB2, kB3;
  kA0 = *(const short8*)&Kb[(size_t)(frow) * HD + fk];
  kA1 = *(const short8*)&Kb[(size_t)(frow) * HD + 32 + fk];
  kA2 = *(const short8*)&Kb[(size_t)(16 + frow) * HD + fk];
  kA3 = *(const short8*)&Kb[(size_t)(16 + frow) * HD + 32 + fk];

  int t = 0;
  for (; t + 1 < tbu; t += 2) {
    FA_BODY(kA0, kA1, kA2, kA3, kB0, kB1, kB2, kB3, t, 0);
    FA_BODY(kB0, kB1, kB2, kB3, kA0, kA1, kA2, kA3, t + 1, 0);
  }
  if (t < tbu) {
    FA_BODY(kA0, kA1, kA2, kA3, kB0, kB1, kB2, kB3, t, 0);
    ++t;
    if (t < tb) {   // diagonal tile, buffer parity B
      FA_BODY(kB0, kB1, kB2, kB3, kA0, kA1, kA2, kA3, t, 1);
    }
  } else if (t < tb) {  // diagonal tile, buffer parity A
    FA_BODY(kA0, kA1, kA2, kA3, kB0, kB1, kB2, kB3, t, 1);
  }

  // denom: sum across quads (k-direction), then transpose to O-row layout
  lp0 += __shfl_xor(lp0, 16); lp0 += __shfl_xor(lp0, 32);
  lp1 += __shfl_xor(lp1, 16); lp1 += __shfl_xor(lp1, 32);
  float lpq0[4], lpq1[4];
#pragma unroll
  for (int r = 0; r < 4; ++r) {
    lpq0[r] = __shfl(lp0, quad * 4 + r);   // every lane holds full sums
    lpq1[r] = __shfl(lp1, quad * 4 + r);
  }

  const size_t obase = ((size_t)b * S_LEN + qm) * HID + (size_t)h * HD;
#pragma unroll
  for (int r = 0; r < 4; ++r) {
    const float i0 = 1.0f / lpq0[r];
    const float i1 = 1.0f / lpq1[r];
    const size_t r0 = obase + (size_t)(quad * 4 + r) * HID;
    const size_t r1 = obase + (size_t)(16 + quad * 4 + r) * HID;
    O[r0 +  0 + frow] = f2bf(o00[r] * i0);
    O[r0 + 16 + frow] = f2bf(o01[r] * i0);
    O[r0 + 32 + frow] = f2bf(o02[r] * i0);
    O[r0 + 48 + frow] = f2bf(o03[r] * i0);
    O[r1 +  0 + frow] = f2bf(o10[r] * i1);
    O[r1 + 16 + frow] = f2bf(o11[r] * i1);
    O[r1 + 32 + frow] = f2bf(o12[r] * i1);
    O[r1 + 48 + frow] = f2bf(o13[r] * i1);
  }
}

// ---------------------------------------------------------------------------
// Workspace layout — 60 MiB:
//   R0 @ 0        (16 MiB): hb (hidden bf16) -> Q  (after gemm1)
//   R1 @ 16 MiB   (12 MiB): wq (w_qkv bf16)  -> wo (after gemm1)
//   R2 @ 28 MiB   (24 MiB): qkv              -> O  (after ln_rope)
//   R3 @ 52 MiB   ( 4 MiB): K
//   R4 @ 56 MiB   ( 4 MiB): Vt
// Output: fp32, written directly by gemm_nt<false>.
// ---------------------------------------------------------------------------
extern "C" void kernel_launch(void* const* d_in, const int* in_sizes, int n_in,
                              void* d_out, int out_size, void* d_ws, size_t ws_size,
                              hipStream_t stream) {
  (void)in_sizes; (void)n_in; (void)out_size; (void)ws_size;
  const int*   pos    = (const int*)d_in[0];
  const float* hidden = (const float*)d_in[1];
  const float* w_qkv  = (const float*)d_in[2];
  const float* q_ln_w = (const float*)d_in[3];
  const float* k_ln_w = (const float*)d_in[4];
  const float* w_o    = (const float*)d_in[5];

  char* ws = (char*)d_ws;
  ushort* hb  = (ushort*)(ws);
  ushort* Q   = (ushort*)(ws);                   // reuse R0
  ushort* wq  = (ushort*)(ws + 16777216);
  ushort* wo  = (ushort*)(ws + 16777216);        // reuse R1
  ushort* qkv = (ushort*)(ws + 29360128);
  ushort* O   = (ushort*)(ws + 29360128);        // reuse R2
  ushort* Kk  = (ushort*)(ws + 54525952);
  ushort* Vt  = (ushort*)(ws + 58720256);

  cvt_f32_bf16<<<dim3(4096), 256, 0, stream>>>(hidden, hb, 8388608 / 8);
  cvt_f32_bf16<<<dim3(3072), 256, 0, stream>>>(w_qkv, wq, 6291456 / 8);
  gemm_nt<true><<<dim3(QKV_N / 128, ROWS / 128), 256, 0, stream>>>(
      hb, wq, qkv, ROWS, QKV_N, HID);
  ln_rope_split<<<dim3(ROWS * 48 / 4), 256, 0, stream>>>(
      qkv, pos, q_ln_w, k_ln_w, Q, Kk, Vt);
  cvt_f32_bf16<<<dim3(2048), 256, 0, stream>>>(w_o, wo, 4194304 / 8);
  flash_attn<<<dim3(2048), 128, 0, stream>>>(Q, Kk, Vt, O);
  gemm_nt<false><<<dim3(HID / 128, ROWS / 128), 256, 0, stream>>>(
      O, wo, d_out, ROWS, HID, HID);
}

// Round 7
// 364.230 us; speedup vs baseline: 1.3693x; 1.1659x over previous
//
#include <hip/hip_runtime.h>
#include <hip/hip_bf16.h>

#define S_LEN 2048
#define HID   2048
#define NH    32
#define NKV   8
#define HD    64
#define ROT   16
#define QKV_N 3072
#define ROWS  4096   // B*S

typedef __attribute__((ext_vector_type(8))) short short8;
typedef __attribute__((ext_vector_type(8))) unsigned short ushort8;
typedef __attribute__((ext_vector_type(4))) float floatx4;

static __device__ __forceinline__ float bf2f(ushort u) {
  union { unsigned int i; float f; } v; v.i = ((unsigned int)u) << 16; return v.f;
}
static __device__ __forceinline__ ushort f2bf(float f) {
  union { __hip_bfloat16 h; ushort u; } v; v.h = __float2bfloat16(f); return v.u;
}

// ---------------------------------------------------------------------------
// fp32 -> bf16 convert, 8 elems/thread (inputs are fp32)
// ---------------------------------------------------------------------------
__global__ __launch_bounds__(256)
void cvt_f32_bf16(const float* __restrict__ in, ushort* __restrict__ out, int n8) {
  const int i = blockIdx.x * 256 + threadIdx.x;
  if (i >= n8) return;
  const float4 a = ((const float4*)in)[2 * i];
  const float4 b = ((const float4*)in)[2 * i + 1];
  ushort8 o;
  o[0] = f2bf(a.x); o[1] = f2bf(a.y); o[2] = f2bf(a.z); o[3] = f2bf(a.w);
  o[4] = f2bf(b.x); o[5] = f2bf(b.y); o[6] = f2bf(b.z); o[7] = f2bf(b.w);
  ((ushort8*)out)[i] = o;
}

// ---------------------------------------------------------------------------
// NT GEMM (m97 structure): 128x128 tile, BK=32, global_load_lds width-16,
// 4 waves x 4x4 mfma_f32_16x16x32_bf16. OUT_BF16 ? bf16 C : fp32 C.
// + XCD-bijective block swizzle (T1); nwg%8==0 for both shapes (768, 512).
// ---------------------------------------------------------------------------
template<bool OUT_BF16>
__global__ __launch_bounds__(256, 2)
void gemm_nt(const ushort* __restrict__ A, const ushort* __restrict__ B,
             void* __restrict__ Cout, int M, int N, int K) {
  __shared__ ushort lA[128 * 32];
  __shared__ ushort lB[128 * 32];
  const int tid  = threadIdx.x;
  const int wave = tid >> 6, lane = tid & 63;
  const int wr = (wave >> 1) * 64, wc = (wave & 1) * 64;
  const int frow = lane & 15, quad = lane >> 4;
  const int fk = quad * 8;
  const int srow = lane >> 2, skk = (lane & 3) * 8;

  // XCD-bijective swizzle of the linear block id
  const int gx  = gridDim.x;
  const int nwg = gx * gridDim.y;
  const int lin = blockIdx.y * gx + blockIdx.x;
  const int cpx = nwg >> 3;
  const int swz = (lin & 7) * cpx + (lin >> 3);
  const int bxi = swz % gx, byi = swz / gx;

  const size_t bm = (size_t)byi * 128;
  const size_t bn = (size_t)bxi * 128;
  const ushort* Ab = A + bm * K;
  const ushort* Bb = B + bn * K;
  floatx4 acc[4][4] = {};

  for (int k0 = 0; k0 < K; k0 += 32) {
    __syncthreads();
    {
      const int c0 = wave * 2;
      const ushort* ga = Ab + (size_t)(c0 * 16 + srow) * K + (k0 + skk);
      const ushort* gb = Bb + (size_t)(c0 * 16 + srow) * K + (k0 + skk);
      __builtin_amdgcn_global_load_lds((const __attribute__((address_space(1))) void*)ga,
          (__attribute__((address_space(3))) void*)&lA[c0 * 512], 16, 0, 0);
      __builtin_amdgcn_global_load_lds((const __attribute__((address_space(1))) void*)gb,
          (__attribute__((address_space(3))) void*)&lB[c0 * 512], 16, 0, 0);
      __builtin_amdgcn_global_load_lds((const __attribute__((address_space(1))) void*)(ga + (size_t)16 * K),
          (__attribute__((address_space(3))) void*)&lA[(c0 + 1) * 512], 16, 0, 0);
      __builtin_amdgcn_global_load_lds((const __attribute__((address_space(1))) void*)(gb + (size_t)16 * K),
          (__attribute__((address_space(3))) void*)&lB[(c0 + 1) * 512], 16, 0, 0);
    }
    __syncthreads();

    short8 af[4], bfr[4];
#pragma unroll
    for (int i = 0; i < 4; ++i)
      af[i] = *(const short8*)&lA[(wr + i * 16 + frow) * 32 + fk];
#pragma unroll
    for (int i = 0; i < 4; ++i)
      bfr[i] = *(const short8*)&lB[(wc + i * 16 + frow) * 32 + fk];
#pragma unroll
    for (int i = 0; i < 4; ++i)
#pragma unroll
      for (int j = 0; j < 4; ++j)
        acc[i][j] = __builtin_amdgcn_mfma_f32_16x16x32_bf16(af[i], bfr[j], acc[i][j], 0, 0, 0);
  }

  const int r0 = quad * 4;
#pragma unroll
  for (int i = 0; i < 4; ++i) {
#pragma unroll
    for (int r = 0; r < 4; ++r) {
      const size_t row = bm + wr + i * 16 + r0 + r;
#pragma unroll
      for (int j = 0; j < 4; ++j) {
        const size_t col = bn + wc + j * 16 + frow;
        if (OUT_BF16) ((ushort*)Cout)[row * N + col] = f2bf(acc[i][j][r]);
        else          ((float*)Cout)[row * N + col] = acc[i][j][r];
      }
    }
  }
}

// ---------------------------------------------------------------------------
// Per-head LayerNorm + partial NeoX RoPE + split. One wave per (row, slot).
// slot 0..31 = q, 32..39 = k, 40..47 = v. LN weights fp32.
// Q -> (b,h,s,d); K -> (b,kv,s,d); V -> (b,kv,d,s) transposed for flash.
// ---------------------------------------------------------------------------
__global__ __launch_bounds__(256)
void ln_rope_split(const ushort* __restrict__ qkv, const int* __restrict__ pos_ids,
                   const float* __restrict__ qw, const float* __restrict__ kw,
                   ushort* __restrict__ Q, ushort* __restrict__ Kk, ushort* __restrict__ Vt) {
  const int gw   = (blockIdx.x * 256 + threadIdx.x) >> 6;
  const int lane = threadIdx.x & 63;
  const int row  = gw / 48;
  const int slot = gw - row * 48;
  const int b = row >> 11, s = row & 2047;
  const float x = bf2f(qkv[(size_t)row * QKV_N + slot * 64 + lane]);

  if (slot < 40) {
    float s1 = x, s2 = x * x;
#pragma unroll
    for (int d = 1; d < 64; d <<= 1) { s1 += __shfl_xor(s1, d); s2 += __shfl_xor(s2, d); }
    const float mu  = s1 * (1.0f / 64.0f);
    const float var = s2 * (1.0f / 64.0f) - mu * mu;
    const float w = (slot < 32) ? qw[slot * 64 + lane] : kw[(slot - 32) * 64 + lane];
    float y = (x - mu) * rsqrtf(var + 1e-5f) * w;
    if (lane < ROT) {
      const int dd = lane & 7;
      const float invf = powf(10000.0f, -(float)dd * 0.125f);
      const float fr = (float)pos_ids[row] * invf;
      const float c = cosf(fr), sn = sinf(fr);
      const float yp = __shfl_xor(y, 8);
      y = (lane < 8) ? (y * c - yp * sn) : (y * c + yp * sn);
    }
    if (slot < 32)
      Q[(((size_t)b * NH + slot) * S_LEN + s) * HD + lane] = f2bf(y);
    else
      Kk[(((size_t)b * NKV + (slot - 32)) * S_LEN + s) * HD + lane] = f2bf(y);
  } else {
    const int kvh = slot - 40;
    Vt[(((size_t)b * NKV + kvh) * HD + lane) * S_LEN + s] = f2bf(x);
  }
}

// ---------------------------------------------------------------------------
// Causal GQA flash attention, FIXED-CAP softmax (no online rescaling):
// LayerNorm bounds |q|,|k| <= 8 -> s = q.k/8 in [-8.1,8.1]; p = exp(s-9)
// cannot overflow; softmax shift-invariance makes it exact.
//
// v8: block = 4 waves = the full GQA group (4 q-heads) of one (b,kvh) at
// ONE qt strip. All 4 waves need IDENTICAL K/V tiles with identical causal
// range -> stage K (32x64) + V (64x32) in LDS once per body via 2x
// global_load_lds (8KB/block-body vs 32KB for 4 independent waves).
// Rationale: v5-v7 all pinned at 137us with all pipes <25% at 2.3 waves/
// SIMD -> correlated stall on per-CU L1 fill (~70 B/cy demand vs ~64 ceiling,
// 1.06GB L2 re-read for 8MB of K/V). 4x traffic cut -> ~32 B/cy.
//  * m97-proven 2-phase loop: stage(next) -> ds_read(cur) -> compute ->
//    barrier. One barrier/body.
//  * K LDS tile XOR-swizzled (c ^= row&7), BOTH sides (rule #21): linear
//    gload_lds dest + inverse-permuted global src + swizzled ds_read.
//    -> ds_read_b128 at the 8-cycle floor. V tile [64][32] naturally
//    conflict-free (8 lanes/bank).
//  * exp folded: p = v_exp_f32(fma(st, 0.125*log2e, -9*log2e)) — 2 ops.
//  * Swapped QK^T (S^T = mfma(K,Q)), in-register P regroup, diagonal-only
//    masking, lane-local denom: unchanged from v7 (passing).
//  * Grid 1024 = (b,kvh)x64 qt; LPT qt-descending; XCD owns 2 kv-heads
//    (1MB K+V, L2-resident). launch_bounds(256,2): cap 256 regs, no spill.
// ---------------------------------------------------------------------------
#define EXPC1 0.180336880111f   // 0.125 * log2(e)
#define EXPC2 -12.9842553680f   // -9 * log2(e)

// Regroup P from S^T-accumulator layout (q=frow, k=quad*4+r; pa=k 0..15,
// pb=k 16..31) into the PV A-operand layout (q=frow, k=quad*8+0..7).
static __device__ __forceinline__ short8 build_pfrag(floatx4 pa, floatx4 pb,
                                                     int frow, int quad) {
  int w0, w1, w2, w3;
  asm("v_cvt_pk_bf16_f32 %0, %1, %2" : "=v"(w0) : "v"(pa[0]), "v"(pa[1]));
  asm("v_cvt_pk_bf16_f32 %0, %1, %2" : "=v"(w1) : "v"(pa[2]), "v"(pa[3]));
  asm("v_cvt_pk_bf16_f32 %0, %1, %2" : "=v"(w2) : "v"(pb[0]), "v"(pb[1]));
  asm("v_cvt_pk_bf16_f32 %0, %1, %2" : "=v"(w3) : "v"(pb[2]), "v"(pb[3]));
  const int sA = frow + ((quad & 1) << 5);   // src quad 0 or 2
  const int sB = sA + 16;                    // src quad 1 or 3
  const int t0 = __shfl(w0, sA), t1 = __shfl(w1, sA);
  const int t2 = __shfl(w0, sB), t3 = __shfl(w1, sB);
  const int u0 = __shfl(w2, sA), u1 = __shfl(w3, sA);
  const int u2 = __shfl(w2, sB), u3 = __shfl(w3, sB);
  const bool lo = quad < 2;                  // k<16 half vs k>=16 half
  union { int i[4]; short8 s; } r;
  r.i[0] = lo ? t0 : u0;
  r.i[1] = lo ? t1 : u1;
  r.i[2] = lo ? t2 : u2;
  r.i[3] = lo ? t3 : u3;
  return r.s;
}

static __device__ __forceinline__ float expfast(float x) {
  float e;
  asm("v_exp_f32 %0, %1" : "=v"(e) : "v"(x));
  return e;
}

// Stage K tile rows jj..jj+31 (pre-swizzled source) and V tile cols jj..jj+31.
#define STAGE(BF, TI)                                                          \
  {                                                                            \
    const int jjs = (TI) * 32;                                                 \
    const ushort* gk = Kb + (size_t)(jjs + krow) * HD + kcol;                  \
    __builtin_amdgcn_global_load_lds(                                          \
        (const __attribute__((address_space(1))) void*)gk,                     \
        (__attribute__((address_space(3))) void*)&lK[BF][wchunk], 16, 0, 0);   \
    const ushort* gv = Vb + (size_t)vrow * S_LEN + jjs + vcol;                 \
    __builtin_amdgcn_global_load_lds(                                          \
        (const __attribute__((address_space(1))) void*)gv,                     \
        (__attribute__((address_space(3))) void*)&lV[BF][wchunk], 16, 0, 0);   \
  }

#define FA_BODY(BF, TI, MASKED)                                                \
  {                                                                            \
    const int jj = (TI) * 32;                                                  \
    const ushort* kb = &lK[BF][0];                                             \
    const ushort* vb = &lV[BF][0];                                             \
    const short8 kc0 = *(const short8*)&kb[frow * 64 + ksw0];                  \
    const short8 kc1 = *(const short8*)&kb[frow * 64 + (ksw0 ^ 32)];           \
    const short8 kc2 = *(const short8*)&kb[(16 + frow) * 64 + ksw0];           \
    const short8 kc3 = *(const short8*)&kb[(16 + frow) * 64 + (ksw0 ^ 32)];    \
    const short8 v0 = *(const short8*)&vb[frow * 32 + fk];                     \
    const short8 v1 = *(const short8*)&vb[(16 + frow) * 32 + fk];              \
    const short8 v2 = *(const short8*)&vb[(32 + frow) * 32 + fk];              \
    const short8 v3 = *(const short8*)&vb[(48 + frow) * 32 + fk];              \
    const floatx4 z = {};                                                      \
    floatx4 st00 = __builtin_amdgcn_mfma_f32_16x16x32_bf16(kc0, q00, z, 0, 0, 0); \
    st00 = __builtin_amdgcn_mfma_f32_16x16x32_bf16(kc1, q01, st00, 0, 0, 0);   \
    floatx4 st01 = __builtin_amdgcn_mfma_f32_16x16x32_bf16(kc2, q00, z, 0, 0, 0); \
    st01 = __builtin_amdgcn_mfma_f32_16x16x32_bf16(kc3, q01, st01, 0, 0, 0);   \
    floatx4 st10 = __builtin_amdgcn_mfma_f32_16x16x32_bf16(kc0, q10, z, 0, 0, 0); \
    st10 = __builtin_amdgcn_mfma_f32_16x16x32_bf16(kc1, q11, st10, 0, 0, 0);   \
    floatx4 st11 = __builtin_amdgcn_mfma_f32_16x16x32_bf16(kc2, q10, z, 0, 0, 0); \
    st11 = __builtin_amdgcn_mfma_f32_16x16x32_bf16(kc3, q11, st11, 0, 0, 0);   \
    floatx4 p00, p01, p10, p11;                                                \
    _Pragma("unroll")                                                          \
    for (int r = 0; r < 4; ++r) {                                              \
      const float e00 = expfast(fmaf(st00[r], EXPC1, EXPC2));                  \
      const float e01 = expfast(fmaf(st01[r], EXPC1, EXPC2));                  \
      const float e10 = expfast(fmaf(st10[r], EXPC1, EXPC2));                  \
      const float e11 = expfast(fmaf(st11[r], EXPC1, EXPC2));                  \
      if (MASKED) {                                                            \
        const int kg0 = jj + quad * 4 + r;                                     \
        const int kg1 = kg0 + 16;                                              \
        p00[r] = (kg0 <= qm + frow)      ? e00 : 0.0f;                         \
        p01[r] = (kg1 <= qm + frow)      ? e01 : 0.0f;                         \
        p10[r] = (kg0 <= qm + 16 + frow) ? e10 : 0.0f;                         \
        p11[r] = (kg1 <= qm + 16 + frow) ? e11 : 0.0f;                         \
      } else {                                                                 \
        p00[r] = e00; p01[r] = e01; p10[r] = e10; p11[r] = e11;                \
      }                                                                        \
      lp0 += p00[r] + p01[r];                                                  \
      lp1 += p10[r] + p11[r];                                                  \
    }                                                                          \
    const short8 pf0 = build_pfrag(p00, p01, frow, quad);                      \
    const short8 pf1 = build_pfrag(p10, p11, frow, quad);                      \
    o00 = __builtin_amdgcn_mfma_f32_16x16x32_bf16(pf0, v0, o00, 0, 0, 0);      \
    o01 = __builtin_amdgcn_mfma_f32_16x16x32_bf16(pf0, v1, o01, 0, 0, 0);      \
    o02 = __builtin_amdgcn_mfma_f32_16x16x32_bf16(pf0, v2, o02, 0, 0, 0);      \
    o03 = __builtin_amdgcn_mfma_f32_16x16x32_bf16(pf0, v3, o03, 0, 0, 0);      \
    o10 = __builtin_amdgcn_mfma_f32_16x16x32_bf16(pf1, v0, o10, 0, 0, 0);      \
    o11 = __builtin_amdgcn_mfma_f32_16x16x32_bf16(pf1, v1, o11, 0, 0, 0);      \
    o12 = __builtin_amdgcn_mfma_f32_16x16x32_bf16(pf1, v2, o12, 0, 0, 0);      \
    o13 = __builtin_amdgcn_mfma_f32_16x16x32_bf16(pf1, v3, o13, 0, 0, 0);      \
  }

__global__ __launch_bounds__(256, 2)
void flash_attn(const ushort* __restrict__ Q, const ushort* __restrict__ Kk,
                const ushort* __restrict__ Vt, ushort* __restrict__ O) {
  __shared__ ushort lK[2][2048];   // [buf][32 rows x 64 d], K-swizzled
  __shared__ ushort lV[2][2048];   // [buf][64 d x 32 s], linear
  const int tid  = threadIdx.x;
  const int wave = tid >> 6, lane = tid & 63;
  const int bb  = blockIdx.x;
  const int xcd = bb & 7;
  const int j   = bb >> 3;                 // 0..127 per XCD
  const int qt  = 63 - (j >> 1);           // LPT: heavy strips dispatch first
  const int pr  = xcd * 2 + (j & 1);       // (b,kvh) pair; 2 kv-heads per XCD
  const int b   = pr >> 3, kvh = pr & 7;
  const int h   = kvh * 4 + wave;          // wave = q-head within GQA group
  const int qm  = qt * 32;
  const int frow = lane & 15, quad = lane >> 4, fk = quad * 8;

  // staging source coords (pre-swizzled K, linear V)
  const int krow = tid >> 3;
  const int kcol = (((tid & 7) ^ (krow & 7)) << 3);
  const int vrow = tid >> 2;
  const int vcol = ((tid & 3) << 3);
  const int wchunk = (tid >> 6) * 512;     // wave-uniform LDS chunk (elems)
  const int ksw0 = ((quad ^ (frow & 7)) << 3);

  const ushort* Qb = Q  + (((size_t)b * NH  + h)   * S_LEN + qm) * HD;
  const ushort* Kb = Kk + ((size_t)b * NKV + kvh)  * S_LEN * HD;
  const ushort* Vb = Vt + ((size_t)b * NKV + kvh)  * HD * S_LEN;

  const short8 q00 = *(const short8*)&Qb[frow * HD + fk];
  const short8 q01 = *(const short8*)&Qb[frow * HD + 32 + fk];
  const short8 q10 = *(const short8*)&Qb[(16 + frow) * HD + fk];
  const short8 q11 = *(const short8*)&Qb[(16 + frow) * HD + 32 + fk];

  floatx4 o00 = {}, o01 = {}, o02 = {}, o03 = {};
  floatx4 o10 = {}, o11 = {}, o12 = {}, o13 = {};
  float lp0 = 0.f, lp1 = 0.f;              // per-lane denom partial (q = frow)

  const int T = qt + 1;                    // tiles; last one is the diagonal

  STAGE(0, 0);
  __syncthreads();
  int buf = 0;
  for (int t = 0; t < T - 1; ++t) {
    STAGE(buf ^ 1, t + 1);
    FA_BODY(buf, t, 0);
    __syncthreads();
    buf ^= 1;
  }
  FA_BODY(buf, T - 1, 1);                  // masked diagonal tile

  // denom: sum across quads (k-direction), then transpose to O-row layout
  lp0 += __shfl_xor(lp0, 16); lp0 += __shfl_xor(lp0, 32);
  lp1 += __shfl_xor(lp1, 16); lp1 += __shfl_xor(lp1, 32);
  float lpq0[4], lpq1[4];
#pragma unroll
  for (int r = 0; r < 4; ++r) {
    lpq0[r] = __shfl(lp0, quad * 4 + r);
    lpq1[r] = __shfl(lp1, quad * 4 + r);
  }

  const size_t obase = ((size_t)b * S_LEN + qm) * HID + (size_t)h * HD;
#pragma unroll
  for (int r = 0; r < 4; ++r) {
    const float i0 = 1.0f / lpq0[r];
    const float i1 = 1.0f / lpq1[r];
    const size_t r0 = obase + (size_t)(quad * 4 + r) * HID;
    const size_t r1 = obase + (size_t)(16 + quad * 4 + r) * HID;
    O[r0 +  0 + frow] = f2bf(o00[r] * i0);
    O[r0 + 16 + frow] = f2bf(o01[r] * i0);
    O[r0 + 32 + frow] = f2bf(o02[r] * i0);
    O[r0 + 48 + frow] = f2bf(o03[r] * i0);
    O[r1 +  0 + frow] = f2bf(o10[r] * i1);
    O[r1 + 16 + frow] = f2bf(o11[r] * i1);
    O[r1 + 32 + frow] = f2bf(o12[r] * i1);
    O[r1 + 48 + frow] = f2bf(o13[r] * i1);
  }
}

// ---------------------------------------------------------------------------
// Workspace layout — 60 MiB:
//   R0 @ 0        (16 MiB): hb (hidden bf16) -> Q  (after gemm1)
//   R1 @ 16 MiB   (12 MiB): wq (w_qkv bf16)  -> wo (after gemm1)
//   R2 @ 28 MiB   (24 MiB): qkv              -> O  (after ln_rope)
//   R3 @ 52 MiB   ( 4 MiB): K
//   R4 @ 56 MiB   ( 4 MiB): Vt
// Output: fp32, written directly by gemm_nt<false>.
// ---------------------------------------------------------------------------
extern "C" void kernel_launch(void* const* d_in, const int* in_sizes, int n_in,
                              void* d_out, int out_size, void* d_ws, size_t ws_size,
                              hipStream_t stream) {
  (void)in_sizes; (void)n_in; (void)out_size; (void)ws_size;
  const int*   pos    = (const int*)d_in[0];
  const float* hidden = (const float*)d_in[1];
  const float* w_qkv  = (const float*)d_in[2];
  const float* q_ln_w = (const float*)d_in[3];
  const float* k_ln_w = (const float*)d_in[4];
  const float* w_o    = (const float*)d_in[5];

  char* ws = (char*)d_ws;
  ushort* hb  = (ushort*)(ws);
  ushort* Q   = (ushort*)(ws);                   // reuse R0
  ushort* wq  = (ushort*)(ws + 16777216);
  ushort* wo  = (ushort*)(ws + 16777216);        // reuse R1
  ushort* qkv = (ushort*)(ws + 29360128);
  ushort* O   = (ushort*)(ws + 29360128);        // reuse R2
  ushort* Kk  = (ushort*)(ws + 54525952);
  ushort* Vt  = (ushort*)(ws + 58720256);

  cvt_f32_bf16<<<dim3(4096), 256, 0, stream>>>(hidden, hb, 8388608 / 8);
  cvt_f32_bf16<<<dim3(3072), 256, 0, stream>>>(w_qkv, wq, 6291456 / 8);
  gemm_nt<true><<<dim3(QKV_N / 128, ROWS / 128), 256, 0, stream>>>(
      hb, wq, qkv, ROWS, QKV_N, HID);
  ln_rope_split<<<dim3(ROWS * 48 / 4), 256, 0, stream>>>(
      qkv, pos, q_ln_w, k_ln_w, Q, Kk, Vt);
  cvt_f32_bf16<<<dim3(2048), 256, 0, stream>>>(w_o, wo, 4194304 / 8);
  flash_attn<<<dim3(1024), 256, 0, stream>>>(Q, Kk, Vt, O);
  gemm_nt<false><<<dim3(HID / 128, ROWS / 128), 256, 0, stream>>>(
      O, wo, d_out, ROWS, HID, HID);
}

// Round 8
// 311.233 us; speedup vs baseline: 1.6024x; 1.1703x over previous
//
#include <hip/hip_runtime.h>
#include <hip/hip_bf16.h>

#define S_LEN 2048
#define HID   2048
#define NH    32
#define NKV   8
#define HD    64
#define ROT   16
#define QKV_N 3072
#define ROWS  4096   // B*S

typedef __attribute__((ext_vector_type(8))) short short8;
typedef __attribute__((ext_vector_type(8))) unsigned short ushort8;
typedef __attribute__((ext_vector_type(4))) float floatx4;

static __device__ __forceinline__ float bf2f(ushort u) {
  union { unsigned int i; float f; } v; v.i = ((unsigned int)u) << 16; return v.f;
}
static __device__ __forceinline__ ushort f2bf(float f) {
  union { __hip_bfloat16 h; ushort u; } v; v.h = __float2bfloat16(f); return v.u;
}

// ---------------------------------------------------------------------------
// fp32 -> bf16 convert, 8 elems/thread (inputs are fp32)
// ---------------------------------------------------------------------------
__global__ __launch_bounds__(256)
void cvt_f32_bf16(const float* __restrict__ in, ushort* __restrict__ out, int n8) {
  const int i = blockIdx.x * 256 + threadIdx.x;
  if (i >= n8) return;
  const float4 a = ((const float4*)in)[2 * i];
  const float4 b = ((const float4*)in)[2 * i + 1];
  ushort8 o;
  o[0] = f2bf(a.x); o[1] = f2bf(a.y); o[2] = f2bf(a.z); o[3] = f2bf(a.w);
  o[4] = f2bf(b.x); o[5] = f2bf(b.y); o[6] = f2bf(b.z); o[7] = f2bf(b.w);
  ((ushort8*)out)[i] = o;
}

// ---------------------------------------------------------------------------
// NT GEMM (m97 structure): 128x128 tile, BK=32, global_load_lds width-16,
// 4 waves x 4x4 mfma_f32_16x16x32_bf16. OUT_BF16 ? bf16 C : fp32 C.
// + XCD-bijective block swizzle (T1); nwg%8==0 for both shapes (768, 512).
// ---------------------------------------------------------------------------
template<bool OUT_BF16>
__global__ __launch_bounds__(256, 2)
void gemm_nt(const ushort* __restrict__ A, const ushort* __restrict__ B,
             void* __restrict__ Cout, int M, int N, int K) {
  __shared__ ushort lA[128 * 32];
  __shared__ ushort lB[128 * 32];
  const int tid  = threadIdx.x;
  const int wave = tid >> 6, lane = tid & 63;
  const int wr = (wave >> 1) * 64, wc = (wave & 1) * 64;
  const int frow = lane & 15, quad = lane >> 4;
  const int fk = quad * 8;
  const int srow = lane >> 2, skk = (lane & 3) * 8;

  // XCD-bijective swizzle of the linear block id
  const int gx  = gridDim.x;
  const int nwg = gx * gridDim.y;
  const int lin = blockIdx.y * gx + blockIdx.x;
  const int cpx = nwg >> 3;
  const int swz = (lin & 7) * cpx + (lin >> 3);
  const int bxi = swz % gx, byi = swz / gx;

  const size_t bm = (size_t)byi * 128;
  const size_t bn = (size_t)bxi * 128;
  const ushort* Ab = A + bm * K;
  const ushort* Bb = B + bn * K;
  floatx4 acc[4][4] = {};

  for (int k0 = 0; k0 < K; k0 += 32) {
    __syncthreads();
    {
      const int c0 = wave * 2;
      const ushort* ga = Ab + (size_t)(c0 * 16 + srow) * K + (k0 + skk);
      const ushort* gb = Bb + (size_t)(c0 * 16 + srow) * K + (k0 + skk);
      __builtin_amdgcn_global_load_lds((const __attribute__((address_space(1))) void*)ga,
          (__attribute__((address_space(3))) void*)&lA[c0 * 512], 16, 0, 0);
      __builtin_amdgcn_global_load_lds((const __attribute__((address_space(1))) void*)gb,
          (__attribute__((address_space(3))) void*)&lB[c0 * 512], 16, 0, 0);
      __builtin_amdgcn_global_load_lds((const __attribute__((address_space(1))) void*)(ga + (size_t)16 * K),
          (__attribute__((address_space(3))) void*)&lA[(c0 + 1) * 512], 16, 0, 0);
      __builtin_amdgcn_global_load_lds((const __attribute__((address_space(1))) void*)(gb + (size_t)16 * K),
          (__attribute__((address_space(3))) void*)&lB[(c0 + 1) * 512], 16, 0, 0);
    }
    __syncthreads();

    short8 af[4], bfr[4];
#pragma unroll
    for (int i = 0; i < 4; ++i)
      af[i] = *(const short8*)&lA[(wr + i * 16 + frow) * 32 + fk];
#pragma unroll
    for (int i = 0; i < 4; ++i)
      bfr[i] = *(const short8*)&lB[(wc + i * 16 + frow) * 32 + fk];
#pragma unroll
    for (int i = 0; i < 4; ++i)
#pragma unroll
      for (int j = 0; j < 4; ++j)
        acc[i][j] = __builtin_amdgcn_mfma_f32_16x16x32_bf16(af[i], bfr[j], acc[i][j], 0, 0, 0);
  }

  const int r0 = quad * 4;
#pragma unroll
  for (int i = 0; i < 4; ++i) {
#pragma unroll
    for (int r = 0; r < 4; ++r) {
      const size_t row = bm + wr + i * 16 + r0 + r;
#pragma unroll
      for (int j = 0; j < 4; ++j) {
        const size_t col = bn + wc + j * 16 + frow;
        if (OUT_BF16) ((ushort*)Cout)[row * N + col] = f2bf(acc[i][j][r]);
        else          ((float*)Cout)[row * N + col] = acc[i][j][r];
      }
    }
  }
}

// ---------------------------------------------------------------------------
// Per-head LayerNorm + partial NeoX RoPE + split — VECTORIZED (v2).
// v1 was 80.8us at VALUBusy=100% (pure VALU-bound): libm powf/cosf/sinf
// per row (Payne-Hanek range reduction), scalar 2B/lane loads, 8x too many
// waves. v2: one wave = 8 slots (512 elems, short8 = 16B/lane coalesced);
// LN reduce = 3 shfl_xor within 8-lane groups; inv_freq = compile-time
// table; trig = __cosf/__sinf (hw v_cos_f32, err ~1e-3 << 0.069 threshold).
// Layout: row = gw/6, sg = gw%6 (sg 0..3 = Q slots, 4 = K, 5 = V);
// lane: head hs = lane>>3, elems de = (lane&7)*8.
// Q -> (b,h,s,d); K -> (b,kv,s,d); V -> (b,kv,d,s) transposed for flash.
// ---------------------------------------------------------------------------
static __device__ __forceinline__ float invf_of(int j) {
  const float t[8] = {1.0f, 0.31622776601683794f, 0.1f, 0.031622776601683791f,
                      0.01f, 0.0031622776601683794f, 0.001f, 0.00031622776601683794f};
  return t[j];
}

__global__ __launch_bounds__(256)
void ln_rope_split(const ushort* __restrict__ qkv, const int* __restrict__ pos_ids,
                   const float* __restrict__ qw, const float* __restrict__ kw,
                   ushort* __restrict__ Q, ushort* __restrict__ Kk, ushort* __restrict__ Vt) {
  const int gw   = (blockIdx.x * 256 + threadIdx.x) >> 6;
  const int lane = threadIdx.x & 63;
  const int row  = gw / 6;
  const int sg   = gw - row * 6;           // 0..3 Q, 4 K, 5 V
  const int b = row >> 11, s = row & 2047;
  const int hs = lane >> 3;                // head within the 8-slot group
  const int de = (lane & 7) * 8;           // elem start within head
  const int slot = sg * 8 + hs;

  const ushort8 xv = *(const ushort8*)&qkv[(size_t)row * QKV_N + sg * 512 + lane * 8];
  float x[8];
#pragma unroll
  for (int j = 0; j < 8; ++j) x[j] = bf2f(xv[j]);

  if (sg == 5) {                           // V: passthrough, transposed store
#pragma unroll
    for (int j = 0; j < 8; ++j)
      Vt[(((size_t)b * NKV + hs) * HD + de + j) * S_LEN + s] = f2bf(x[j]);
    return;
  }

  float s1 = 0.f, s2 = 0.f;
#pragma unroll
  for (int j = 0; j < 8; ++j) { s1 += x[j]; s2 += x[j] * x[j]; }
  s1 += __shfl_xor(s1, 1); s2 += __shfl_xor(s2, 1);
  s1 += __shfl_xor(s1, 2); s2 += __shfl_xor(s2, 2);
  s1 += __shfl_xor(s1, 4); s2 += __shfl_xor(s2, 4);
  const float mu  = s1 * 0.015625f;
  const float var = s2 * 0.015625f - mu * mu;
  const float rs  = rsqrtf(var + 1e-5f);

  const float* wb = (sg < 4) ? &qw[slot * 64 + de] : &kw[hs * 64 + de];
  float y[8];
#pragma unroll
  for (int j = 0; j < 8; ++j) y[j] = (x[j] - mu) * rs * wb[j];

  // RoPE on d<16: lane (lane&7)==0 holds x1 (d=j), ==1 holds x2 (d=8+j)
  const int lp = lane & 7;
  const float pos = (float)pos_ids[row];
  float yp[8];
#pragma unroll
  for (int j = 0; j < 8; ++j) yp[j] = __shfl_xor(y[j], 1);
  if (lp < 2) {
#pragma unroll
    for (int j = 0; j < 8; ++j) {
      const float fr = pos * invf_of(j);
      const float c = __cosf(fr), sn = __sinf(fr);
      y[j] = (lp == 0) ? (y[j] * c - yp[j] * sn) : (y[j] * c + yp[j] * sn);
    }
  }

  ushort8 o;
#pragma unroll
  for (int j = 0; j < 8; ++j) o[j] = f2bf(y[j]);
  if (sg < 4)
    *(ushort8*)&Q[(((size_t)b * NH + slot) * S_LEN + s) * HD + de] = o;
  else
    *(ushort8*)&Kk[(((size_t)b * NKV + hs) * S_LEN + s) * HD + de] = o;
}

// ---------------------------------------------------------------------------
// Causal GQA flash attention, FIXED-CAP softmax (no online rescaling):
// LayerNorm bounds |q|,|k| <= 8 -> s = q.k/8 in [-8.1,8.1]; p = exp(s-9)
// cannot overflow; softmax shift-invariance makes it exact.
//
// v8: block = 4 waves = the full GQA group (4 q-heads) of one (b,kvh) at
// ONE qt strip; K (32x64) + V (64x32) staged in LDS once per body via
// global_load_lds (4x traffic cut vs independent waves). m97 2-phase loop;
// K tile XOR-swizzled both-sides; swapped QK^T; in-register P regroup;
// diagonal-only masking; folded exp (fma + v_exp_f32).
// ---------------------------------------------------------------------------
#define EXPC1 0.180336880111f   // 0.125 * log2(e)
#define EXPC2 -12.9842553680f   // -9 * log2(e)

// Regroup P from S^T-accumulator layout (q=frow, k=quad*4+r; pa=k 0..15,
// pb=k 16..31) into the PV A-operand layout (q=frow, k=quad*8+0..7).
static __device__ __forceinline__ short8 build_pfrag(floatx4 pa, floatx4 pb,
                                                     int frow, int quad) {
  int w0, w1, w2, w3;
  asm("v_cvt_pk_bf16_f32 %0, %1, %2" : "=v"(w0) : "v"(pa[0]), "v"(pa[1]));
  asm("v_cvt_pk_bf16_f32 %0, %1, %2" : "=v"(w1) : "v"(pa[2]), "v"(pa[3]));
  asm("v_cvt_pk_bf16_f32 %0, %1, %2" : "=v"(w2) : "v"(pb[0]), "v"(pb[1]));
  asm("v_cvt_pk_bf16_f32 %0, %1, %2" : "=v"(w3) : "v"(pb[2]), "v"(pb[3]));
  const int sA = frow + ((quad & 1) << 5);   // src quad 0 or 2
  const int sB = sA + 16;                    // src quad 1 or 3
  const int t0 = __shfl(w0, sA), t1 = __shfl(w1, sA);
  const int t2 = __shfl(w0, sB), t3 = __shfl(w1, sB);
  const int u0 = __shfl(w2, sA), u1 = __shfl(w3, sA);
  const int u2 = __shfl(w2, sB), u3 = __shfl(w3, sB);
  const bool lo = quad < 2;                  // k<16 half vs k>=16 half
  union { int i[4]; short8 s; } r;
  r.i[0] = lo ? t0 : u0;
  r.i[1] = lo ? t1 : u1;
  r.i[2] = lo ? t2 : u2;
  r.i[3] = lo ? t3 : u3;
  return r.s;
}

static __device__ __forceinline__ float expfast(float x) {
  float e;
  asm("v_exp_f32 %0, %1" : "=v"(e) : "v"(x));
  return e;
}

// Stage K tile rows jj..jj+31 (pre-swizzled source) and V tile cols jj..jj+31.
#define STAGE(BF, TI)                                                          \
  {                                                                            \
    const int jjs = (TI) * 32;                                                 \
    const ushort* gk = Kb + (size_t)(jjs + krow) * HD + kcol;                  \
    __builtin_amdgcn_global_load_lds(                                          \
        (const __attribute__((address_space(1))) void*)gk,                     \
        (__attribute__((address_space(3))) void*)&lK[BF][wchunk], 16, 0, 0);   \
    const ushort* gv = Vb + (size_t)vrow * S_LEN + jjs + vcol;                 \
    __builtin_amdgcn_global_load_lds(                                          \
        (const __attribute__((address_space(1))) void*)gv,                     \
        (__attribute__((address_space(3))) void*)&lV[BF][wchunk], 16, 0, 0);   \
  }

#define FA_BODY(BF, TI, MASKED)                                                \
  {                                                                            \
    const int jj = (TI) * 32;                                                  \
    const ushort* kb = &lK[BF][0];                                             \
    const ushort* vb = &lV[BF][0];                                             \
    const short8 kc0 = *(const short8*)&kb[frow * 64 + ksw0];                  \
    const short8 kc1 = *(const short8*)&kb[frow * 64 + (ksw0 ^ 32)];           \
    const short8 kc2 = *(const short8*)&kb[(16 + frow) * 64 + ksw0];           \
    const short8 kc3 = *(const short8*)&kb[(16 + frow) * 64 + (ksw0 ^ 32)];    \
    const short8 v0 = *(const short8*)&vb[frow * 32 + fk];                     \
    const short8 v1 = *(const short8*)&vb[(16 + frow) * 32 + fk];              \
    const short8 v2 = *(const short8*)&vb[(32 + frow) * 32 + fk];              \
    const short8 v3 = *(const short8*)&vb[(48 + frow) * 32 + fk];              \
    const floatx4 z = {};                                                      \
    floatx4 st00 = __builtin_amdgcn_mfma_f32_16x16x32_bf16(kc0, q00, z, 0, 0, 0); \
    st00 = __builtin_amdgcn_mfma_f32_16x16x32_bf16(kc1, q01, st00, 0, 0, 0);   \
    floatx4 st01 = __builtin_amdgcn_mfma_f32_16x16x32_bf16(kc2, q00, z, 0, 0, 0); \
    st01 = __builtin_amdgcn_mfma_f32_16x16x32_bf16(kc3, q01, st01, 0, 0, 0);   \
    floatx4 st10 = __builtin_amdgcn_mfma_f32_16x16x32_bf16(kc0, q10, z, 0, 0, 0); \
    st10 = __builtin_amdgcn_mfma_f32_16x16x32_bf16(kc1, q11, st10, 0, 0, 0);   \
    floatx4 st11 = __builtin_amdgcn_mfma_f32_16x16x32_bf16(kc2, q10, z, 0, 0, 0); \
    st11 = __builtin_amdgcn_mfma_f32_16x16x32_bf16(kc3, q11, st11, 0, 0, 0);   \
    floatx4 p00, p01, p10, p11;                                                \
    _Pragma("unroll")                                                          \
    for (int r = 0; r < 4; ++r) {                                              \
      const float e00 = expfast(fmaf(st00[r], EXPC1, EXPC2));                  \
      const float e01 = expfast(fmaf(st01[r], EXPC1, EXPC2));                  \
      const float e10 = expfast(fmaf(st10[r], EXPC1, EXPC2));                  \
      const float e11 = expfast(fmaf(st11[r], EXPC1, EXPC2));                  \
      if (MASKED) {                                                            \
        const int kg0 = jj + quad * 4 + r;                                     \
        const int kg1 = kg0 + 16;                                              \
        p00[r] = (kg0 <= qm + frow)      ? e00 : 0.0f;                         \
        p01[r] = (kg1 <= qm + frow)      ? e01 : 0.0f;                         \
        p10[r] = (kg0 <= qm + 16 + frow) ? e10 : 0.0f;                         \
        p11[r] = (kg1 <= qm + 16 + frow) ? e11 : 0.0f;                         \
      } else {                                                                 \
        p00[r] = e00; p01[r] = e01; p10[r] = e10; p11[r] = e11;                \
      }                                                                        \
      lp0 += p00[r] + p01[r];                                                  \
      lp1 += p10[r] + p11[r];                                                  \
    }                                                                          \
    const short8 pf0 = build_pfrag(p00, p01, frow, quad);                      \
    const short8 pf1 = build_pfrag(p10, p11, frow, quad);                      \
    o00 = __builtin_amdgcn_mfma_f32_16x16x32_bf16(pf0, v0, o00, 0, 0, 0);      \
    o01 = __builtin_amdgcn_mfma_f32_16x16x32_bf16(pf0, v1, o01, 0, 0, 0);      \
    o02 = __builtin_amdgcn_mfma_f32_16x16x32_bf16(pf0, v2, o02, 0, 0, 0);      \
    o03 = __builtin_amdgcn_mfma_f32_16x16x32_bf16(pf0, v3, o03, 0, 0, 0);      \
    o10 = __builtin_amdgcn_mfma_f32_16x16x32_bf16(pf1, v0, o10, 0, 0, 0);      \
    o11 = __builtin_amdgcn_mfma_f32_16x16x32_bf16(pf1, v1, o11, 0, 0, 0);      \
    o12 = __builtin_amdgcn_mfma_f32_16x16x32_bf16(pf1, v2, o12, 0, 0, 0);      \
    o13 = __builtin_amdgcn_mfma_f32_16x16x32_bf16(pf1, v3, o13, 0, 0, 0);      \
  }

__global__ __launch_bounds__(256, 2)
void flash_attn(const ushort* __restrict__ Q, const ushort* __restrict__ Kk,
                const ushort* __restrict__ Vt, ushort* __restrict__ O) {
  __shared__ ushort lK[2][2048];   // [buf][32 rows x 64 d], K-swizzled
  __shared__ ushort lV[2][2048];   // [buf][64 d x 32 s], linear
  const int tid  = threadIdx.x;
  const int wave = tid >> 6, lane = tid & 63;
  const int bb  = blockIdx.x;
  const int xcd = bb & 7;
  const int j   = bb >> 3;                 // 0..127 per XCD
  const int qt  = 63 - (j >> 1);           // LPT: heavy strips dispatch first
  const int pr  = xcd * 2 + (j & 1);       // (b,kvh) pair; 2 kv-heads per XCD
  const int b   = pr >> 3, kvh = pr & 7;
  const int h   = kvh * 4 + wave;          // wave = q-head within GQA group
  const int qm  = qt * 32;
  const int frow = lane & 15, quad = lane >> 4, fk = quad * 8;

  // staging source coords (pre-swizzled K, linear V)
  const int krow = tid >> 3;
  const int kcol = (((tid & 7) ^ (krow & 7)) << 3);
  const int vrow = tid >> 2;
  const int vcol = ((tid & 3) << 3);
  const int wchunk = (tid >> 6) * 512;     // wave-uniform LDS chunk (elems)
  const int ksw0 = ((quad ^ (frow & 7)) << 3);

  const ushort* Qb = Q  + (((size_t)b * NH  + h)   * S_LEN + qm) * HD;
  const ushort* Kb = Kk + ((size_t)b * NKV + kvh)  * S_LEN * HD;
  const ushort* Vb = Vt + ((size_t)b * NKV + kvh)  * HD * S_LEN;

  const short8 q00 = *(const short8*)&Qb[frow * HD + fk];
  const short8 q01 = *(const short8*)&Qb[frow * HD + 32 + fk];
  const short8 q10 = *(const short8*)&Qb[(16 + frow) * HD + fk];
  const short8 q11 = *(const short8*)&Qb[(16 + frow) * HD + 32 + fk];

  floatx4 o00 = {}, o01 = {}, o02 = {}, o03 = {};
  floatx4 o10 = {}, o11 = {}, o12 = {}, o13 = {};
  float lp0 = 0.f, lp1 = 0.f;              // per-lane denom partial (q = frow)

  const int T = qt + 1;                    // tiles; last one is the diagonal

  STAGE(0, 0);
  __syncthreads();
  int buf = 0;
  for (int t = 0; t < T - 1; ++t) {
    STAGE(buf ^ 1, t + 1);
    FA_BODY(buf, t, 0);
    __syncthreads();
    buf ^= 1;
  }
  FA_BODY(buf, T - 1, 1);                  // masked diagonal tile

  // denom: sum across quads (k-direction), then transpose to O-row layout
  lp0 += __shfl_xor(lp0, 16); lp0 += __shfl_xor(lp0, 32);
  lp1 += __shfl_xor(lp1, 16); lp1 += __shfl_xor(lp1, 32);
  float lpq0[4], lpq1[4];
#pragma unroll
  for (int r = 0; r < 4; ++r) {
    lpq0[r] = __shfl(lp0, quad * 4 + r);
    lpq1[r] = __shfl(lp1, quad * 4 + r);
  }

  const size_t obase = ((size_t)b * S_LEN + qm) * HID + (size_t)h * HD;
#pragma unroll
  for (int r = 0; r < 4; ++r) {
    const float i0 = 1.0f / lpq0[r];
    const float i1 = 1.0f / lpq1[r];
    const size_t r0 = obase + (size_t)(quad * 4 + r) * HID;
    const size_t r1 = obase + (size_t)(16 + quad * 4 + r) * HID;
    O[r0 +  0 + frow] = f2bf(o00[r] * i0);
    O[r0 + 16 + frow] = f2bf(o01[r] * i0);
    O[r0 + 32 + frow] = f2bf(o02[r] * i0);
    O[r0 + 48 + frow] = f2bf(o03[r] * i0);
    O[r1 +  0 + frow] = f2bf(o10[r] * i1);
    O[r1 + 16 + frow] = f2bf(o11[r] * i1);
    O[r1 + 32 + frow] = f2bf(o12[r] * i1);
    O[r1 + 48 + frow] = f2bf(o13[r] * i1);
  }
}

// ---------------------------------------------------------------------------
// Workspace layout — 60 MiB:
//   R0 @ 0        (16 MiB): hb (hidden bf16) -> Q  (after gemm1)
//   R1 @ 16 MiB   (12 MiB): wq (w_qkv bf16)  -> wo (after gemm1)
//   R2 @ 28 MiB   (24 MiB): qkv              -> O  (after ln_rope)
//   R3 @ 52 MiB   ( 4 MiB): K
//   R4 @ 56 MiB   ( 4 MiB): Vt
// Output: fp32, written directly by gemm_nt<false>.
// ---------------------------------------------------------------------------
extern "C" void kernel_launch(void* const* d_in, const int* in_sizes, int n_in,
                              void* d_out, int out_size, void* d_ws, size_t ws_size,
                              hipStream_t stream) {
  (void)in_sizes; (void)n_in; (void)out_size; (void)ws_size;
  const int*   pos    = (const int*)d_in[0];
  const float* hidden = (const float*)d_in[1];
  const float* w_qkv  = (const float*)d_in[2];
  const float* q_ln_w = (const float*)d_in[3];
  const float* k_ln_w = (const float*)d_in[4];
  const float* w_o    = (const float*)d_in[5];

  char* ws = (char*)d_ws;
  ushort* hb  = (ushort*)(ws);
  ushort* Q   = (ushort*)(ws);                   // reuse R0
  ushort* wq  = (ushort*)(ws + 16777216);
  ushort* wo  = (ushort*)(ws + 16777216);        // reuse R1
  ushort* qkv = (ushort*)(ws + 29360128);
  ushort* O   = (ushort*)(ws + 29360128);        // reuse R2
  ushort* Kk  = (ushort*)(ws + 54525952);
  ushort* Vt  = (ushort*)(ws + 58720256);

  cvt_f32_bf16<<<dim3(4096), 256, 0, stream>>>(hidden, hb, 8388608 / 8);
  cvt_f32_bf16<<<dim3(3072), 256, 0, stream>>>(w_qkv, wq, 6291456 / 8);
  gemm_nt<true><<<dim3(QKV_N / 128, ROWS / 128), 256, 0, stream>>>(
      hb, wq, qkv, ROWS, QKV_N, HID);
  ln_rope_split<<<dim3(ROWS * 6 / 4), 256, 0, stream>>>(
      qkv, pos, q_ln_w, k_ln_w, Q, Kk, Vt);
  cvt_f32_bf16<<<dim3(2048), 256, 0, stream>>>(w_o, wo, 4194304 / 8);
  flash_attn<<<dim3(1024), 256, 0, stream>>>(Q, Kk, Vt, O);
  gemm_nt<false><<<dim3(HID / 128, ROWS / 128), 256, 0, stream>>>(
      O, wo, d_out, ROWS, HID, HID);
}